// Round 14
// baseline (1596.103 us; speedup 1.0000x reference)
//
#include <hip/hip_runtime.h>
#include <math.h>

// ---------------- problem constants ----------------
#define DIMD  512
#define NSEQ  4096
#define BATCH 2
#define HEADS 8
#define DHEAD 64
#define MLAND 256
#define BH    (BATCH*HEADS)      // 16
#define QSCALE 0.125f
#define LN_EPS 1e-5f
#define KCONV 33

typedef __attribute__((ext_vector_type(8))) short bf16x8;
typedef __attribute__((ext_vector_type(4))) float f32x4;

// ---------------- workspace layout (MB offsets) ----------------
#define WB(p, mb) ((char*)(p) + (size_t)(mb) * 1048576ull)

// ---------------- helpers ----------------
__device__ __forceinline__ unsigned short f2b(float f) {
  unsigned u = __float_as_uint(f);
  return (unsigned short)((u + 0x7FFFu + ((u >> 16) & 1u)) >> 16);
}
__device__ __forceinline__ float b2f(unsigned short h) {
  return __uint_as_float(((unsigned)h) << 16);
}

__device__ __forceinline__ float block_red(float v, float* s4, bool sum) {
#pragma unroll
  for (int o = 32; o; o >>= 1) {
    float t = __shfl_xor(v, o);
    v = sum ? v + t : fmaxf(v, t);
  }
  int wid = threadIdx.x >> 6;
  if ((threadIdx.x & 63) == 0) s4[wid] = v;
  __syncthreads();
  float r = sum ? (s4[0] + s4[1] + s4[2] + s4[3])
                : fmaxf(fmaxf(s4[0], s4[1]), fmaxf(s4[2], s4[3]));
  __syncthreads();
  return r;
}

// async global->LDS, 16B per lane; LDS dest = wave-uniform base + lane*16
__device__ __forceinline__ void gload16(const unsigned short* g, short* lds) {
  __builtin_amdgcn_global_load_lds(
      (const __attribute__((address_space(1))) void*)g,
      (__attribute__((address_space(3))) void*)lds, 16, 0, 0);
}

// stage ROWS x 32 bf16 tile (row-major, contiguous k) into LDS via global_load_lds.
// lane l <-> row l/4, col (l%4)*16B  == linear row-major [ROWS][32] shorts.
template<int ROWS>
__device__ __forceinline__ void stage_lds(const unsigned short* __restrict__ g, int ld,
                                          short* lds, int tid) {
  int l = tid & 63, w = tid >> 6;
  int r_in = l >> 2, c8 = (l & 3) * 8;
  constexpr int PER = ROWS / 64;   // instructions per wave
#pragma unroll
  for (int p = 0; p < PER; ++p) {
    int r0 = (w * PER + p) * 16;
    gload16(g + (size_t)(r0 + r_in) * ld + c8, lds + r0 * 32);
  }
}

// wave computes 64x64 from LDS tiles As[.][32], Bs[.][32] (both [row][k] bf16)
__device__ __forceinline__ void mma_step32(const short* As, const short* Bs,
                                           int wrow, int wcol, int l, f32x4 acc[4][4]) {
  int lr = l & 15, lk = (l >> 4) * 8;
  bf16x8 af[4], bf_[4];
#pragma unroll
  for (int f = 0; f < 4; ++f) {
    af[f]  = *(const bf16x8*)&As[(wrow + f * 16 + lr) * 32 + lk];
    bf_[f] = *(const bf16x8*)&Bs[(wcol + f * 16 + lr) * 32 + lk];
  }
#pragma unroll
  for (int i = 0; i < 4; ++i)
#pragma unroll
    for (int j = 0; j < 4; ++j)
      acc[i][j] = __builtin_amdgcn_mfma_f32_16x16x32_bf16(af[i], bf_[j], acc[i][j], 0, 0, 0);
}

// device-scope sense-reversal grid barrier (256 blocks; proven R8 machinery)
__device__ __forceinline__ void grid_bar(unsigned* bar, unsigned* gen) {
  __syncthreads();
  if (threadIdx.x == 0) {
    unsigned my = __hip_atomic_load(gen, __ATOMIC_ACQUIRE, __HIP_MEMORY_SCOPE_AGENT);
    unsigned a = __hip_atomic_fetch_add(bar, 1u, __ATOMIC_ACQ_REL, __HIP_MEMORY_SCOPE_AGENT);
    if (a == 255u) {
      __hip_atomic_store(bar, 0u, __ATOMIC_RELAXED, __HIP_MEMORY_SCOPE_AGENT);
      __hip_atomic_fetch_add(gen, 1u, __ATOMIC_RELEASE, __HIP_MEMORY_SCOPE_AGENT);
    } else {
      while (__hip_atomic_load(gen, __ATOMIC_ACQUIRE, __HIP_MEMORY_SCOPE_AGENT) == my)
        __builtin_amdgcn_s_sleep(2);
    }
  }
  __syncthreads();
}

// ---------------- kernels ----------------

__global__ void k_init(unsigned* scal) {
  if (threadIdx.x < 4) scal[threadIdx.x] = 0u;
}

// fused: blocks [0,2048) LayerNorm -> bf16 xn; blocks [2048,6144) weight conversion
__global__ __launch_bounds__(256) void k_ln_wconv(const float* __restrict__ x,
                                                  const float* __restrict__ w,
                                                  const float* __restrict__ b,
                                                  const float* __restrict__ qkvw,
                                                  const float* __restrict__ outw,
                                                  unsigned short* __restrict__ xnh,
                                                  unsigned short* __restrict__ wqh,
                                                  unsigned short* __restrict__ owh) {
  if (blockIdx.x >= 2048) {
    int idx = (blockIdx.x - 2048) * 256 + threadIdx.x;
    if (idx < 786432) wqh[idx] = f2b(qkvw[idx]);
    else owh[idx - 786432] = f2b(outw[idx - 786432]);
    return;
  }
  int lane = threadIdx.x & 63;
  int row = blockIdx.x * 4 + (threadIdx.x >> 6);
  const float* xr = x + (size_t)row * DIMD;
  float4 v0 = *(const float4*)&xr[lane * 8];
  float4 v1 = *(const float4*)&xr[lane * 8 + 4];
  float s  = v0.x + v0.y + v0.z + v0.w + v1.x + v1.y + v1.z + v1.w;
  float ss = v0.x*v0.x + v0.y*v0.y + v0.z*v0.z + v0.w*v0.w
           + v1.x*v1.x + v1.y*v1.y + v1.z*v1.z + v1.w*v1.w;
#pragma unroll
  for (int o = 32; o; o >>= 1) { s += __shfl_xor(s, o); ss += __shfl_xor(ss, o); }
  float mu = s * (1.f / 512.f);
  float var = ss * (1.f / 512.f) - mu * mu;
  float rstd = rsqrtf(var + LN_EPS);
  float4 w0 = *(const float4*)&w[lane * 8];
  float4 w1 = *(const float4*)&w[lane * 8 + 4];
  float4 b0 = *(const float4*)&b[lane * 8];
  float4 b1 = *(const float4*)&b[lane * 8 + 4];
  float o0x = (v0.x - mu) * rstd * w0.x + b0.x;
  float o0y = (v0.y - mu) * rstd * w0.y + b0.y;
  float o0z = (v0.z - mu) * rstd * w0.z + b0.z;
  float o0w = (v0.w - mu) * rstd * w0.w + b0.w;
  float o1x = (v1.x - mu) * rstd * w1.x + b1.x;
  float o1y = (v1.y - mu) * rstd * w1.y + b1.y;
  float o1z = (v1.z - mu) * rstd * w1.z + b1.z;
  float o1w = (v1.w - mu) * rstd * w1.w + b1.w;
  uint4 pk;
  pk.x = (unsigned)f2b(o0x) | ((unsigned)f2b(o0y) << 16);
  pk.y = (unsigned)f2b(o0z) | ((unsigned)f2b(o0w) << 16);
  pk.z = (unsigned)f2b(o1x) | ((unsigned)f2b(o1y) << 16);
  pk.w = (unsigned)f2b(o1z) | ((unsigned)f2b(o1w) << 16);
  *(uint4*)&xnh[(size_t)row * DIMD + lane * 8] = pk;
}

// QKV: C[m,c]=sum_k xn[m,k]*W[c,k]; outputs bf16 only: qh, kh, vh (row), vTh (transposed)
__global__ __launch_bounds__(256) void k_qkv_mfma(const unsigned short* __restrict__ xnh,
                                                  const unsigned short* __restrict__ wqh,
                                                  unsigned short* __restrict__ qh,
                                                  unsigned short* __restrict__ kh,
                                                  unsigned short* __restrict__ vh,
                                                  unsigned short* __restrict__ vTh) {
  __shared__ short As[128 * 32], Bs[128 * 32];
  int tid = threadIdx.x, l = tid & 63, wid = tid >> 6;
  int wrow = (wid >> 1) * 64, wcol = (wid & 1) * 64;
  int m0 = blockIdx.y * 128, c0 = blockIdx.x * 128;
  f32x4 acc[4][4] = {};
  for (int k0 = 0; k0 < 512; k0 += 32) {
    __syncthreads();
    stage_lds<128>(xnh + (size_t)m0 * 512 + k0, 512, As, tid);
    stage_lds<128>(wqh + (size_t)c0 * 512 + k0, 512, Bs, tid);
    __syncthreads();
    mma_step32(As, Bs, wrow, wcol, l, acc);
  }
  const int which = c0 >> 9;
#pragma unroll
  for (int i = 0; i < 4; ++i) {
#pragma unroll
    for (int j = 0; j < 4; ++j) {
      int col = c0 + wcol + j * 16 + (l & 15);
      int hh = (col >> 6) & 7, d = col & 63;
      int m_base = m0 + wrow + i * 16 + ((l >> 4) * 4);
      int bb = m_base >> 12, n0 = m_base & 4095;
      size_t hb = (size_t)(bb * 8 + hh);
      if (which == 0) {
#pragma unroll
        for (int r = 0; r < 4; ++r)
          qh[(hb * 4096 + n0 + r) * 64 + d] = f2b(acc[i][j][r] * QSCALE);
      } else if (which == 1) {
#pragma unroll
        for (int r = 0; r < 4; ++r)
          kh[(hb * 4096 + n0 + r) * 64 + d] = f2b(acc[i][j][r]);
      } else {
        ushort4 hv;
        hv.x = f2b(acc[i][j][0]); hv.y = f2b(acc[i][j][1]);
        hv.z = f2b(acc[i][j][2]); hv.w = f2b(acc[i][j][3]);
#pragma unroll
        for (int r = 0; r < 4; ++r)
          vh[(hb * 4096 + n0 + r) * 64 + d] = (&hv.x)[r];
        *(ushort4*)&vTh[(hb * 64 + d) * 4096 + n0] = hv;
      }
    }
  }
}

// landmark means (l=16) from bf16 q/k; outputs f32 + bf16
__global__ __launch_bounds__(256) void k_land(const unsigned short* __restrict__ q,
                                              const unsigned short* __restrict__ k,
                                              float* __restrict__ ql,
                                              float* __restrict__ kl,
                                              unsigned short* __restrict__ qlh,
                                              unsigned short* __restrict__ klh) {
  int idx = blockIdx.x * 256 + threadIdx.x;
  int sel = idx >= (BH * MLAND * DHEAD);
  int e = sel ? idx - BH * MLAND * DHEAD : idx;
  int bh = e >> 14; int m = (e >> 6) & 255; int d = e & 63;
  const unsigned short* src = sel ? k : q;
  size_t base = ((size_t)bh * 4096 + m * 16) * 64 + d;
  float s = 0;
#pragma unroll
  for (int t = 0; t < 16; ++t) s += b2f(src[base + t * 64]);
  float val = s * (1.f / 16.f);
  (sel ? kl : ql)[e] = val;
  (sel ? klh : qlh)[e] = f2b(val);
}

// sim2 + row softmax -> a2 fp32 + bf16
__global__ __launch_bounds__(256) void k_sim2(const float* __restrict__ ql,
                                              const float* __restrict__ kl,
                                              float* __restrict__ a2,
                                              unsigned short* __restrict__ a2h) {
  __shared__ float qs[64];
  __shared__ float s4[4];
  int i = blockIdx.x, bh = blockIdx.y, tid = threadIdx.x;
  if (tid < 16) ((float4*)qs)[tid] = ((const float4*)(ql + ((size_t)bh * 256 + i) * 64))[tid];
  __syncthreads();
  const float* kr = kl + ((size_t)bh * 256 + tid) * 64;
  float s = 0;
#pragma unroll
  for (int d = 0; d < 64; d += 4) {
    float4 kv = *(const float4*)&kr[d];
    s += qs[d] * kv.x + qs[d + 1] * kv.y + qs[d + 2] * kv.z + qs[d + 3] * kv.w;
  }
  float mx = block_red(s, s4, false);
  float p = expf(s - mx);
  float tot = block_red(p, s4, true);
  float val = p / tot;
  a2[((size_t)bh * 256 + i) * 256 + tid] = val;
  a2h[((size_t)bh * 256 + i) * 256 + tid] = f2b(val);
}

__global__ __launch_bounds__(256) void k_pinv_red(const float* __restrict__ a2,
                                                  unsigned* __restrict__ scal) {
  __shared__ float s4[4];
  int bh = blockIdx.x, tid = threadIdx.x;
  const float* m = a2 + (size_t)bh * 65536;
  float cs = 0;
  for (int i = 0; i < 256; ++i) cs += fabsf(m[(size_t)i * 256 + tid]);
  float rs = 0;
  const float* row = m + (size_t)tid * 256;
  for (int j = 0; j < 256; j += 4) {
    float4 v = *(const float4*)&row[j];
    rs += fabsf(v.x) + fabsf(v.y) + fabsf(v.z) + fabsf(v.w);
  }
  float mc = block_red(cs, s4, false);
  float mr = block_red(rs, s4, false);
  if (tid == 0) {
    atomicMax(&scal[0], __float_as_uint(mr));
    atomicMax(&scal[1], __float_as_uint(mc));
  }
}

// z0 = a2^T / (R*C) in bf16, plus transposed copy
__global__ __launch_bounds__(256) void k_z0h(const float* __restrict__ a2,
                                             const unsigned* __restrict__ scal,
                                             unsigned short* __restrict__ zh,
                                             unsigned short* __restrict__ zTh) {
  int idx = blockIdx.x * 256 + threadIdx.x;
  float inv = 1.f / (__uint_as_float(scal[0]) * __uint_as_float(scal[1]));
  int bh = idx >> 16, r = (idx >> 8) & 255, c = idx & 255;
  zh[idx]  = f2b(a2[((size_t)bh << 16) + (c << 8) + r] * inv);
  zTh[idx] = f2b(a2[idx] * inv);
}

// one pinv phase: exact k_pg2 body (64x64 tile, full-K LDS staging, Horner order)
__device__ __forceinline__ void pg2_phase(const unsigned short* __restrict__ A,
                                          const unsigned short* __restrict__ Bsrc,
                                          unsigned short* C, unsigned short* CT,
                                          float g, float bI, float s,
                                          short* As, short* Bs, int tid) {
  int l = tid & 63, w = tid >> 6;
  int bh = blockIdx.x & 15, t = blockIdx.x >> 4;
  int i0 = (t >> 2) * 64, j0 = (t & 3) * 64;
  A += (size_t)bh * 65536; Bsrc += (size_t)bh * 65536;

#pragma unroll
  for (int ks = 0; ks < 8; ++ks)
    stage_lds<64>(A + (size_t)i0 * 256 + ks * 32, 256, As + ks * 2048, tid);

#pragma unroll
  for (int u = tid; u < 2048; u += 256) {
    int r = u >> 5, q8 = u & 31;
    int ks = q8 >> 2, p = q8 & 3;
    uint4 vv = *(const uint4*)(Bsrc + (size_t)(j0 + r) * 256 + q8 * 8);
    unsigned short* e = (unsigned short*)&vv;
    int n = j0 + r, kb = q8 * 8;
#pragma unroll
    for (int q = 0; q < 8; ++q) {
      float f = b2f(e[q]) * g + ((n == kb + q) ? bI : 0.f);
      e[q] = f2b(f);
    }
    *(uint4*)(Bs + ks * 2048 + r * 32 + p * 8) = vv;
  }
  __syncthreads();

  int lr = l & 15, lk = (l >> 4) * 8;
  f32x4 acc[4] = {};
#pragma unroll
  for (int ks = 0; ks < 8; ++ks) {
    const short* Ac = As + ks * 2048;
    const short* Bc = Bs + ks * 2048;
    bf16x8 af = *(const bf16x8*)&Ac[(w * 16 + lr) * 32 + lk];
#pragma unroll
    for (int j = 0; j < 4; ++j) {
      bf16x8 bf_ = *(const bf16x8*)&Bc[(j * 16 + lr) * 32 + lk];
      acc[j] = __builtin_amdgcn_mfma_f32_16x16x32_bf16(af, bf_, acc[j], 0, 0, 0);
    }
  }

#pragma unroll
  for (int j = 0; j < 4; ++j) {
    int col = j0 + j * 16 + lr;
    int row0 = i0 + w * 16 + (l >> 4) * 4;
    ushort4 hv;
    hv.x = f2b(acc[j][0] * s); hv.y = f2b(acc[j][1] * s);
    hv.z = f2b(acc[j][2] * s); hv.w = f2b(acc[j][3] * s);
    if (CT) *(ushort4*)&CT[(size_t)bh * 65536 + (size_t)col * 256 + row0] = hv;
    if (C) {
      unsigned short* cb = C + (size_t)bh * 65536 + (size_t)row0 * 256 + col;
      cb[0] = hv.x; cb[256] = hv.y; cb[512] = hv.z; cb[768] = hv.w;
    }
  }
  __threadfence();
}

// persistent pinv chain: 24 phases, 256 blocks, grid barrier between phases
__global__ __launch_bounds__(256, 1) void k_pinv_chain2(const unsigned short* __restrict__ a2h,
                                                        unsigned short* zA, unsigned short* zAT,
                                                        unsigned short* zB, unsigned short* zBT,
                                                        unsigned short* Am, unsigned short* AmT,
                                                        unsigned short* W2T, unsigned short* W4T,
                                                        unsigned* bar, unsigned* gen) {
  __shared__ short As[8 * 64 * 32], Bs[8 * 64 * 32];
  int tid = threadIdx.x;
  unsigned short *zc = zA, *zcT = zAT, *zn = zB, *znT = zBT;
#pragma unroll 1
  for (int it = 0; it < 6; ++it) {
    pg2_phase(a2h, zcT, Am, AmT, 1.f, 0.f, 1.f, As, Bs, tid);
    grid_bar(bar, gen);
    pg2_phase(Am, AmT, (unsigned short*)nullptr, W2T, -1.f, 7.f, 1.f, As, Bs, tid);
    grid_bar(bar, gen);
    pg2_phase(Am, W2T, (unsigned short*)nullptr, W4T, -1.f, 15.f, 1.f, As, Bs, tid);
    grid_bar(bar, gen);
    pg2_phase(zc, W4T, zn, znT, -1.f, 13.f, 0.25f, As, Bs, tid);
    if (it != 5) grid_bar(bar, gen);
    unsigned short* t;
    t = zc; zc = zn; zn = t;
    t = zcT; zcT = znT; znT = t;
  }
  // final z (row-major) lands in zA after 6 iterations (even swap count)
}

// sim3 = q_land @ k^T -> bf16 [bh][256][4096] (raw scores, softmax deferred)
__global__ __launch_bounds__(256) void k_sim3_mfma(const unsigned short* __restrict__ qlh,
                                                   const unsigned short* __restrict__ kh,
                                                   unsigned short* __restrict__ sim3h) {
  __shared__ short As[128 * 32], Bs[128 * 32];
  int tid = threadIdx.x, l = tid & 63, wid = tid >> 6;
  int wrow = (wid >> 1) * 64, wcol = (wid & 1) * 64;
  int bh = blockIdx.z;
  int m0 = blockIdx.y * 128, n0 = blockIdx.x * 128;
  const unsigned short* A = qlh + (size_t)bh * 256 * 64;
  const unsigned short* B = kh + (size_t)bh * 4096 * 64;
  f32x4 acc[4][4] = {};
  for (int k0 = 0; k0 < 64; k0 += 32) {
    __syncthreads();
    stage_lds<128>(A + (size_t)m0 * 64 + k0, 64, As, tid);
    stage_lds<128>(B + (size_t)n0 * 64 + k0, 64, Bs, tid);
    __syncthreads();
    mma_step32(As, Bs, wrow, wcol, l, acc);
  }
  unsigned short* Cm = sim3h + (size_t)bh * 1048576;
#pragma unroll
  for (int i = 0; i < 4; ++i)
#pragma unroll
    for (int j = 0; j < 4; ++j) {
      int col = n0 + wcol + j * 16 + (l & 15);
      int row0 = m0 + wrow + i * 16 + (l >> 4) * 4;
#pragma unroll
      for (int r = 0; r < 4; ++r)
        Cm[(size_t)(row0 + r) * 4096 + col] = f2b(acc[i][j][r]);
    }
}

// per-row max and 1/sum(exp) of sim3 rows (read-only) -> rs[bh*256+m] = {max, inv}
__global__ __launch_bounds__(256) void k_rowstat(const unsigned short* __restrict__ sim,
                                                 float* __restrict__ rs) {
  __shared__ float s4[4];
  int m = blockIdx.x, bh = blockIdx.y, tid = threadIdx.x;
  const unsigned short* row = sim + ((size_t)bh * 256 + m) * 4096;
  float v[16];
  float mx = -1e30f;
#pragma unroll
  for (int i = 0; i < 16; ++i) { v[i] = b2f(row[i * 256 + tid]); mx = fmaxf(mx, v[i]); }
  mx = block_red(mx, s4, false);
  float ssum = 0;
#pragma unroll
  for (int i = 0; i < 16; ++i) ssum += expf(v[i] - mx);
  ssum = block_red(ssum, s4, true);
  if (tid == 0) {
    rs[(size_t)(bh * 256 + m) * 2]     = mx;
    rs[(size_t)(bh * 256 + m) * 2 + 1] = 1.f / ssum;
  }
}

// a3 @ v split-K (kc=16, chunk=256, 8 inner steps), softmax on A-stage,
// issue-early prefetch of next chunk's A-registers overlapping MFMA (T14).
__global__ __launch_bounds__(256) void k_a3v_mfma(const unsigned short* __restrict__ a3h,
                                                  const unsigned short* __restrict__ vTh,
                                                  const float* __restrict__ rs,
                                                  float* __restrict__ part) {
  __shared__ short As[256 * 32], Bs[64 * 32];
  int tid = threadIdx.x, l = tid & 63, wid = tid >> 6;
  int wrow = wid * 64, wcol = 0;
  int kc = blockIdx.x, bh = blockIdx.z;     // kc in [0,16)
  const unsigned short* A = a3h + (size_t)bh * 1048576 + kc * 256;
  const unsigned short* B = vTh + (size_t)bh * 262144 + kc * 256;
  rs += (size_t)bh * 512;
  const int rA = tid >> 2, cA8 = (tid & 3) * 8;   // per-thread A slot
  f32x4 acc[4][4] = {};
  uint4 pre[4];
  // prefetch chunk 0
#pragma unroll
  for (int p = 0; p < 4; ++p)
    pre[p] = *(const uint4*)(A + (size_t)(rA + 64 * p) * 4096 + cA8);
#pragma unroll 1
  for (int ks = 0; ks < 8; ++ks) {
    __syncthreads();
    // transform + write prefetched A to LDS
#pragma unroll
    for (int p = 0; p < 4; ++p) {
      int r = rA + 64 * p;
      uint4 vv = pre[p];
      unsigned short* e = (unsigned short*)&vv;
      float m_ = rs[r * 2], inv_ = rs[r * 2 + 1];
#pragma unroll
      for (int q = 0; q < 8; ++q)
        e[q] = f2b(expf(b2f(e[q]) - m_) * inv_);
      *(uint4*)(As + r * 32 + cA8) = vv;
    }
    stage_lds<64>(B + ks * 32, 4096, Bs, tid);
    __syncthreads();
    if (ks < 7) {
      // issue next chunk's loads before MFMA (overlap)
#pragma unroll
      for (int p = 0; p < 4; ++p)
        pre[p] = *(const uint4*)(A + (size_t)(rA + 64 * p) * 4096 + (ks + 1) * 32 + cA8);
    }
    mma_step32(As, Bs, wrow, wcol, l, acc);
  }
  float* P = part + ((size_t)(kc * 16 + bh)) * 16384;
#pragma unroll
  for (int i = 0; i < 4; ++i)
#pragma unroll
    for (int j = 0; j < 4; ++j) {
      int col = j * 16 + (l & 15);
      int row0 = wrow + i * 16 + (l >> 4) * 4;
#pragma unroll
      for (int r = 0; r < 4; ++r)
        P[(size_t)(row0 + r) * 64 + col] = acc[i][j][r];
    }
}

// reduce split-K partials (16) -> a3vT bf16 [bh][64 d][256 m]
// coalesced: d in low bits of thread index -> consecutive lanes read consecutive floats
__global__ __launch_bounds__(256) void k_a3v_redT(const float* __restrict__ part,
                                                  unsigned short* __restrict__ a3vT) {
  int idx = blockIdx.x * 256 + threadIdx.x;   // 262144
  int d = idx & 63, m = (idx >> 6) & 255, bh = idx >> 14;
  float s = 0;
#pragma unroll
  for (int c = 0; c < 16; ++c) s += part[((size_t)(c * 16 + bh) * 256 + m) * 64 + d];
  a3vT[(size_t)bh * 16384 + d * 256 + m] = f2b(s);
}

// wm = z @ a3v -> wmT bf16 [bh][64 d][256 m]
__global__ __launch_bounds__(256) void k_wm_mfma(const unsigned short* __restrict__ zh,
                                                 const unsigned short* __restrict__ a3vTh,
                                                 unsigned short* __restrict__ wmTh) {
  __shared__ short As[256 * 32], Bs[64 * 32];
  int tid = threadIdx.x, l = tid & 63, wid = tid >> 6;
  int wrow = wid * 64, wcol = 0;
  int bh = blockIdx.z;
  const unsigned short* A = zh + (size_t)bh * 65536;
  const unsigned short* B = a3vTh + (size_t)bh * 16384;
  f32x4 acc[4][4] = {};
  for (int k0 = 0; k0 < 256; k0 += 32) {
    __syncthreads();
    stage_lds<256>(A + k0, 256, As, tid);
    stage_lds<64>(B + k0, 256, Bs, tid);
    __syncthreads();
    mma_step32(As, Bs, wrow, wcol, l, acc);
  }
  unsigned short* W = wmTh + (size_t)bh * 16384;
#pragma unroll
  for (int i = 0; i < 4; ++i)
#pragma unroll
    for (int j = 0; j < 4; ++j) {
      int col = j * 16 + (l & 15);                 // d
      int row0 = wrow + i * 16 + (l >> 4) * 4;     // m
#pragma unroll
      for (int r = 0; r < 4; ++r)
        W[(size_t)col * 256 + row0 + r] = f2b(acc[i][j][r]);
    }
}

// ---------------- fused attention tail, MFMA ----------------
// block = 128 tokens x 1 head, 512 threads (8 waves, 16 rows each)
#define FSM_Q    0
#define FSM_KL   16384
#define FSM_WMT  0
#define FSM_P    32768
#define FSM_OUT  0
#define FSM_V    32768
__global__ __launch_bounds__(512) void k_fused_mfma(const unsigned short* __restrict__ qh,
                                                    const unsigned short* __restrict__ klh,
                                                    const unsigned short* __restrict__ wmTh,
                                                    const unsigned short* __restrict__ vh,
                                                    const float* __restrict__ cw,
                                                    unsigned short* __restrict__ yh) {
  __shared__ char sm[55808];
  int tid = threadIdx.x, l = tid & 63, w = tid >> 6;
  int h = blockIdx.y, b = blockIdx.z, bh = b * HEADS + h;
  int n0 = blockIdx.x * 128;
  const char* qg = (const char*)(qh + ((size_t)bh * 4096 + n0) * 64);
  const char* kg = (const char*)(klh + (size_t)bh * 256 * 64);

  // stage q (swizzled) and kl (swizzled)
#pragma unroll
  for (int u = tid; u < 1024; u += 512) {
    int row = u >> 3, cb = (u & 7) * 16;
    *(uint4*)(sm + FSM_Q + row * 128 + (cb ^ ((row & 7) << 4))) =
        *(const uint4*)(qg + row * 128 + cb);
  }
#pragma unroll
  for (int u = tid; u < 2048; u += 512) {
    int row = u >> 3, cb = (u & 7) * 16;
    *(uint4*)(sm + FSM_KL + row * 128 + (cb ^ ((row & 7) << 4))) =
        *(const uint4*)(kg + row * 128 + cb);
  }
  __syncthreads();

  int lr = l & 15, lkb = (l >> 4) * 16;
  int arow = 16 * w + lr;
  int aswz = (arow & 7) << 4;
  f32x4 acc[16] = {};
#pragma unroll
  for (int ks = 0; ks < 2; ++ks) {
    bf16x8 af = *(const bf16x8*)(sm + FSM_Q + arow * 128 + ((ks * 64 + lkb) ^ aswz));
#pragma unroll
    for (int j = 0; j < 16; ++j) {
      int brow = j * 16 + lr;
      bf16x8 bf_ = *(const bf16x8*)(sm + FSM_KL + brow * 128 + ((ks * 64 + lkb) ^ ((brow & 7) << 4)));
      acc[j] = __builtin_amdgcn_mfma_f32_16x16x32_bf16(af, bf_, acc[j], 0, 0, 0);
    }
  }

  // in-register row softmax (row on 16 lanes x 16 j-frags)
#pragma unroll
  for (int r = 0; r < 4; ++r) {
    float mx = -1e30f;
#pragma unroll
    for (int j = 0; j < 16; ++j) mx = fmaxf(mx, acc[j][r]);
#pragma unroll
    for (int o = 8; o; o >>= 1) mx = fmaxf(mx, __shfl_xor(mx, o));
    float s = 0.f;
#pragma unroll
    for (int j = 0; j < 16; ++j) { float e = expf(acc[j][r] - mx); acc[j][r] = e; s += e; }
#pragma unroll
    for (int o = 8; o; o >>= 1) s += __shfl_xor(s, o);
    float inv = 1.f / s;
#pragma unroll
    for (int j = 0; j < 16; ++j) acc[j][r] *= inv;
  }
  __syncthreads();

  // stage wmT (swizzled)
  const char* wg = (const char*)(wmTh + (size_t)bh * 16384);
#pragma unroll
  for (int u = tid; u < 2048; u += 512) {
    int row = u >> 5, cb = (u & 31) * 16;
    *(uint4*)(sm + FSM_WMT + row * 512 + (cb ^ ((row & 7) << 4))) =
        *(const uint4*)(wg + row * 512 + cb);
  }

  f32x4 acc2[4] = {};
  int prow0 = 16 * w + (l >> 4) * 4;
#pragma unroll
  for (int mc = 0; mc < 4; ++mc) {
    __syncthreads();
#pragma unroll
    for (int j2 = 0; j2 < 4; ++j2)
#pragma unroll
      for (int r = 0; r < 4; ++r) {
        int row = prow0 + r;
        int colb = (j2 * 16 + lr) * 2;
        *(unsigned short*)(sm + FSM_P + row * 128 + (colb ^ ((row & 7) << 4))) =
            f2b(acc[mc * 4 + j2][r]);
      }
    __syncthreads();
#pragma unroll
    for (int ks = 0; ks < 2; ++ks) {
      bf16x8 af = *(const bf16x8*)(sm + FSM_P + arow * 128 + ((ks * 64 + lkb) ^ aswz));
#pragma unroll
      for (int j = 0; j < 4; ++j) {
        int brow = j * 16 + lr;
        bf16x8 bf_ = *(const bf16x8*)(sm + FSM_WMT + brow * 512 +
                                      ((mc * 128 + ks * 64 + lkb) ^ ((brow & 7) << 4)));
        acc2[j] = __builtin_amdgcn_mfma_f32_16x16x32_bf16(af, bf_, acc2[j], 0, 0, 0);
      }
    }
  }
  __syncthreads();

  // park PV result in LDS f32
#pragma unroll
  for (int j = 0; j < 4; ++j)
#pragma unroll
    for (int r = 0; r < 4; ++r)
      *(float*)(sm + FSM_OUT + (prow0 + r) * 256 + (j * 16 + lr) * 4) = acc2[j][r];

  // stage v halo bf16 [160 rows x 128B] at 144B stride
  const char* vg = (const char*)(vh + (size_t)bh * 4096 * 64);
#pragma unroll
  for (int u = tid; u < 1280; u += 512) {
    int row = u >> 3, cb = (u & 7) * 16;
    int n = n0 - 16 + row;
    uint4 vv; vv.x = 0; vv.y = 0; vv.z = 0; vv.w = 0;
    if (n >= 0 && n < 4096) vv = *(const uint4*)(vg + (size_t)n * 128 + cb);
    *(uint4*)(sm + FSM_V + row * 144 + cb) = vv;
  }
  __syncthreads();

  // conv + add + store
#pragma unroll
  for (int u = tid; u < 1024; u += 512) {
    int row = u >> 3, d8 = (u & 7) * 8;
    float r8[8] = {};
#pragma unroll 1
    for (int t = 0; t < KCONV; ++t) {
      float wt = cw[h * KCONV + t];  // uniform -> scalar load
      ushort4 a0 = *(const ushort4*)(sm + FSM_V + (row + t) * 144 + d8 * 2);
      ushort4 a1 = *(const ushort4*)(sm + FSM_V + (row + t) * 144 + d8 * 2 + 8);
      r8[0] += wt * b2f(a0.x); r8[1] += wt * b2f(a0.y);
      r8[2] += wt * b2f(a0.z); r8[3] += wt * b2f(a0.w);
      r8[4] += wt * b2f(a1.x); r8[5] += wt * b2f(a1.y);
      r8[6] += wt * b2f(a1.z); r8[7] += wt * b2f(a1.w);
    }
    const float* ol = (const float*)(sm + FSM_OUT + row * 256 + d8 * 4);
    ushort4 s0, s1;
    s0.x = f2b(r8[0] + ol[0]); s0.y = f2b(r8[1] + ol[1]);
    s0.z = f2b(r8[2] + ol[2]); s0.w = f2b(r8[3] + ol[3]);
    s1.x = f2b(r8[4] + ol[4]); s1.y = f2b(r8[5] + ol[5]);
    s1.z = f2b(r8[6] + ol[6]); s1.w = f2b(r8[7] + ol[7]);
    unsigned short* yp = yh + ((size_t)b * 4096 + n0 + row) * 512 + h * 64 + d8;
    *(ushort4*)yp = s0;
    *(ushort4*)(yp + 4) = s1;
  }
}

// out = x + y @ out_w^T + out_b  (MFMA)
__global__ __launch_bounds__(256) void k_outproj_mfma(const unsigned short* __restrict__ yh,
                                                      const unsigned short* __restrict__ owh,
                                                      const float* __restrict__ bias,
                                                      const float* __restrict__ x,
                                                      float* __restrict__ out) {
  __shared__ short As[128 * 32], Bs[128 * 32];
  int tid = threadIdx.x, l = tid & 63, wid = tid >> 6;
  int wrow = (wid >> 1) * 64, wcol = (wid & 1) * 64;
  int m0 = blockIdx.y * 128, c0 = blockIdx.x * 128;
  f32x4 acc[4][4] = {};
  for (int k0 = 0; k0 < 512; k0 += 32) {
    __syncthreads();
    stage_lds<128>(yh + (size_t)m0 * 512 + k0, 512, As, tid);
    stage_lds<128>(owh + (size_t)c0 * 512 + k0, 512, Bs, tid);
    __syncthreads();
    mma_step32(As, Bs, wrow, wcol, l, acc);
  }
#pragma unroll
  for (int i = 0; i < 4; ++i)
#pragma unroll
    for (int j = 0; j < 4; ++j) {
      int col = c0 + wcol + j * 16 + (l & 15);
      int row0 = m0 + wrow + i * 16 + (l >> 4) * 4;
      float bb = bias[col];
#pragma unroll
      for (int r = 0; r < 4; ++r) {
        size_t o = (size_t)(row0 + r) * 512 + col;
        out[o] = acc[i][j][r] + x[o] + bb;
      }
    }
}

// ---------------- launcher ----------------
extern "C" void kernel_launch(void* const* d_in, const int* in_sizes, int n_in,
                              void* d_out, int out_size, void* d_ws, size_t ws_size,
                              hipStream_t stream) {
  const float* x      = (const float*)d_in[0];
  const float* ln_w   = (const float*)d_in[1];
  const float* ln_b   = (const float*)d_in[2];
  const float* qkv_w  = (const float*)d_in[3];
  const float* out_w  = (const float*)d_in[4];
  const float* out_b  = (const float*)d_in[5];
  const float* conv_w = (const float*)d_in[6];
  float* out = (float*)d_out;

  unsigned short* vh  = (unsigned short*)WB(d_ws, 0);   // 8.4 MB
  float* part = (float*)WB(d_ws, 12);   // 16 partials: 16.8 MB (12..30)
  float* ql   = (float*)WB(d_ws, 48);
  float* kl   = (float*)WB(d_ws, 49);
  float* a2   = (float*)WB(d_ws, 50);
  float* rs   = (float*)WB(d_ws, 62);   // 32 KB row stats
  unsigned* scal = (unsigned*)WB(d_ws, 63);
  unsigned short* xnh  = (unsigned short*)WB(d_ws, 64);
  unsigned short* wqh  = (unsigned short*)WB(d_ws, 72);
  unsigned short* owh  = (unsigned short*)WB(d_ws, 74);
  unsigned short* kh   = (unsigned short*)WB(d_ws, 76);
  unsigned short* vTh  = (unsigned short*)WB(d_ws, 84);
  unsigned short* qlh  = (unsigned short*)WB(d_ws, 92);
  unsigned short* a2h  = (unsigned short*)WB(d_ws, 93);
  unsigned short* zA   = (unsigned short*)WB(d_ws, 95);
  unsigned short* zAT  = (unsigned short*)WB(d_ws, 97);
  unsigned short* zB   = (unsigned short*)WB(d_ws, 99);
  unsigned short* zBT  = (unsigned short*)WB(d_ws, 101);
  unsigned short* Am   = (unsigned short*)WB(d_ws, 103);
  unsigned short* AmT  = (unsigned short*)WB(d_ws, 105);
  unsigned short* W2T  = (unsigned short*)WB(d_ws, 107);
  unsigned short* W4T  = (unsigned short*)WB(d_ws, 109);
  unsigned short* sim3h= (unsigned short*)WB(d_ws, 111);
  unsigned short* a3vTh= (unsigned short*)WB(d_ws, 143);
  unsigned short* yh   = (unsigned short*)WB(d_ws, 144);
  unsigned short* qhb  = (unsigned short*)WB(d_ws, 152);
  unsigned short* klhb = (unsigned short*)WB(d_ws, 168);
  unsigned short* wmTh = (unsigned short*)WB(d_ws, 169);

  k_init<<<1, 64, 0, stream>>>(scal);
  k_ln_wconv<<<6144, 256, 0, stream>>>(x, ln_w, ln_b, qkv_w, out_w, xnh, wqh, owh);
  k_qkv_mfma<<<dim3(12, 64), 256, 0, stream>>>(xnh, wqh, qhb, kh, vh, vTh);
  k_land<<<2048, 256, 0, stream>>>(qhb, kh, ql, kl, qlh, klhb);
  k_sim2<<<dim3(256, 16), 256, 0, stream>>>(ql, kl, a2, a2h);
  k_pinv_red<<<16, 256, 0, stream>>>(a2, scal);
  k_z0h<<<4096, 256, 0, stream>>>(a2, scal, zA, zAT);

  k_pinv_chain2<<<256, 256, 0, stream>>>(a2h, zA, zAT, zB, zBT, Am, AmT, W2T, W4T,
                                         scal + 2, scal + 3);

  k_sim3_mfma<<<dim3(32, 2, 16), 256, 0, stream>>>(qlh, kh, sim3h);
  k_rowstat<<<dim3(256, 16), 256, 0, stream>>>(sim3h, rs);
  k_a3v_mfma<<<dim3(16, 1, 16), 256, 0, stream>>>(sim3h, vTh, rs, part);
  k_a3v_redT<<<1024, 256, 0, stream>>>(part, a3vTh);
  k_wm_mfma<<<dim3(1, 1, 16), 256, 0, stream>>>(zA, a3vTh, wmTh);
  k_fused_mfma<<<dim3(32, 8, 2), 512, 0, stream>>>(qhb, klhb, wmTh, vh, conv_w, yh);
  k_outproj_mfma<<<dim3(4, 64), 256, 0, stream>>>(yh, owh, out_b, x, out);
}

// Round 15
// 327.034 us; speedup vs baseline: 4.8805x; 4.8805x over previous
//
#include <hip/hip_runtime.h>
#include <math.h>

// ---------------- problem constants ----------------
#define DIMD  512
#define NSEQ  4096
#define BATCH 2
#define HEADS 8
#define DHEAD 64
#define MLAND 256
#define BH    (BATCH*HEADS)      // 16
#define QSCALE 0.125f
#define LN_EPS 1e-5f
#define KCONV 33

typedef __attribute__((ext_vector_type(8))) short bf16x8;
typedef __attribute__((ext_vector_type(4))) float f32x4;

// ---------------- workspace layout (MB offsets) ----------------
#define WB(p, mb) ((char*)(p) + (size_t)(mb) * 1048576ull)

// ---------------- helpers ----------------
__device__ __forceinline__ unsigned short f2b(float f) {
  unsigned u = __float_as_uint(f);
  return (unsigned short)((u + 0x7FFFu + ((u >> 16) & 1u)) >> 16);
}
__device__ __forceinline__ float b2f(unsigned short h) {
  return __uint_as_float(((unsigned)h) << 16);
}

__device__ __forceinline__ float block_red(float v, float* s4, bool sum) {
#pragma unroll
  for (int o = 32; o; o >>= 1) {
    float t = __shfl_xor(v, o);
    v = sum ? v + t : fmaxf(v, t);
  }
  int wid = threadIdx.x >> 6;
  if ((threadIdx.x & 63) == 0) s4[wid] = v;
  __syncthreads();
  float r = sum ? (s4[0] + s4[1] + s4[2] + s4[3])
                : fmaxf(fmaxf(s4[0], s4[1]), fmaxf(s4[2], s4[3]));
  __syncthreads();
  return r;
}

// async global->LDS, 16B per lane; LDS dest = wave-uniform base + lane*16
__device__ __forceinline__ void gload16(const unsigned short* g, short* lds) {
  __builtin_amdgcn_global_load_lds(
      (const __attribute__((address_space(1))) void*)g,
      (__attribute__((address_space(3))) void*)lds, 16, 0, 0);
}

// stage ROWS x 32 bf16 tile (row-major, contiguous k) into LDS via global_load_lds.
// lane l <-> row l/4, col (l%4)*16B  == linear row-major [ROWS][32] shorts.
template<int ROWS>
__device__ __forceinline__ void stage_lds(const unsigned short* __restrict__ g, int ld,
                                          short* lds, int tid) {
  int l = tid & 63, w = tid >> 6;
  int r_in = l >> 2, c8 = (l & 3) * 8;
  constexpr int PER = ROWS / 64;   // instructions per wave
#pragma unroll
  for (int p = 0; p < PER; ++p) {
    int r0 = (w * PER + p) * 16;
    gload16(g + (size_t)(r0 + r_in) * ld + c8, lds + r0 * 32);
  }
}

// wave computes 64x64 from LDS tiles As[.][32], Bs[.][32] (both [row][k] bf16)
__device__ __forceinline__ void mma_step32(const short* As, const short* Bs,
                                           int wrow, int wcol, int l, f32x4 acc[4][4]) {
  int lr = l & 15, lk = (l >> 4) * 8;
  bf16x8 af[4], bf_[4];
#pragma unroll
  for (int f = 0; f < 4; ++f) {
    af[f]  = *(const bf16x8*)&As[(wrow + f * 16 + lr) * 32 + lk];
    bf_[f] = *(const bf16x8*)&Bs[(wcol + f * 16 + lr) * 32 + lk];
  }
#pragma unroll
  for (int i = 0; i < 4; ++i)
#pragma unroll
    for (int j = 0; j < 4; ++j)
      acc[i][j] = __builtin_amdgcn_mfma_f32_16x16x32_bf16(af[i], bf_[j], acc[i][j], 0, 0, 0);
}

// ---------------- kernels ----------------

__global__ void k_init(unsigned* scal) {
  if (threadIdx.x < 4) scal[threadIdx.x] = 0u;
}

// fused: blocks [0,2048) LayerNorm -> bf16 xn; blocks [2048,6144) weight conversion
__global__ __launch_bounds__(256) void k_ln_wconv(const float* __restrict__ x,
                                                  const float* __restrict__ w,
                                                  const float* __restrict__ b,
                                                  const float* __restrict__ qkvw,
                                                  const float* __restrict__ outw,
                                                  unsigned short* __restrict__ xnh,
                                                  unsigned short* __restrict__ wqh,
                                                  unsigned short* __restrict__ owh) {
  if (blockIdx.x >= 2048) {
    int idx = (blockIdx.x - 2048) * 256 + threadIdx.x;
    if (idx < 786432) wqh[idx] = f2b(qkvw[idx]);
    else owh[idx - 786432] = f2b(outw[idx - 786432]);
    return;
  }
  int lane = threadIdx.x & 63;
  int row = blockIdx.x * 4 + (threadIdx.x >> 6);
  const float* xr = x + (size_t)row * DIMD;
  float4 v0 = *(const float4*)&xr[lane * 8];
  float4 v1 = *(const float4*)&xr[lane * 8 + 4];
  float s  = v0.x + v0.y + v0.z + v0.w + v1.x + v1.y + v1.z + v1.w;
  float ss = v0.x*v0.x + v0.y*v0.y + v0.z*v0.z + v0.w*v0.w
           + v1.x*v1.x + v1.y*v1.y + v1.z*v1.z + v1.w*v1.w;
#pragma unroll
  for (int o = 32; o; o >>= 1) { s += __shfl_xor(s, o); ss += __shfl_xor(ss, o); }
  float mu = s * (1.f / 512.f);
  float var = ss * (1.f / 512.f) - mu * mu;
  float rstd = rsqrtf(var + LN_EPS);
  float4 w0 = *(const float4*)&w[lane * 8];
  float4 w1 = *(const float4*)&w[lane * 8 + 4];
  float4 b0 = *(const float4*)&b[lane * 8];
  float4 b1 = *(const float4*)&b[lane * 8 + 4];
  float o0x = (v0.x - mu) * rstd * w0.x + b0.x;
  float o0y = (v0.y - mu) * rstd * w0.y + b0.y;
  float o0z = (v0.z - mu) * rstd * w0.z + b0.z;
  float o0w = (v0.w - mu) * rstd * w0.w + b0.w;
  float o1x = (v1.x - mu) * rstd * w1.x + b1.x;
  float o1y = (v1.y - mu) * rstd * w1.y + b1.y;
  float o1z = (v1.z - mu) * rstd * w1.z + b1.z;
  float o1w = (v1.w - mu) * rstd * w1.w + b1.w;
  uint4 pk;
  pk.x = (unsigned)f2b(o0x) | ((unsigned)f2b(o0y) << 16);
  pk.y = (unsigned)f2b(o0z) | ((unsigned)f2b(o0w) << 16);
  pk.z = (unsigned)f2b(o1x) | ((unsigned)f2b(o1y) << 16);
  pk.w = (unsigned)f2b(o1z) | ((unsigned)f2b(o1w) << 16);
  *(uint4*)&xnh[(size_t)row * DIMD + lane * 8] = pk;
}

// QKV: C[m,c]=sum_k xn[m,k]*W[c,k]; outputs bf16 only: qh, kh, vh (row), vTh (transposed)
__global__ __launch_bounds__(256) void k_qkv_mfma(const unsigned short* __restrict__ xnh,
                                                  const unsigned short* __restrict__ wqh,
                                                  unsigned short* __restrict__ qh,
                                                  unsigned short* __restrict__ kh,
                                                  unsigned short* __restrict__ vh,
                                                  unsigned short* __restrict__ vTh) {
  __shared__ short As[128 * 32], Bs[128 * 32];
  int tid = threadIdx.x, l = tid & 63, wid = tid >> 6;
  int wrow = (wid >> 1) * 64, wcol = (wid & 1) * 64;
  int m0 = blockIdx.y * 128, c0 = blockIdx.x * 128;
  f32x4 acc[4][4] = {};
  for (int k0 = 0; k0 < 512; k0 += 32) {
    __syncthreads();
    stage_lds<128>(xnh + (size_t)m0 * 512 + k0, 512, As, tid);
    stage_lds<128>(wqh + (size_t)c0 * 512 + k0, 512, Bs, tid);
    __syncthreads();
    mma_step32(As, Bs, wrow, wcol, l, acc);
  }
  const int which = c0 >> 9;
#pragma unroll
  for (int i = 0; i < 4; ++i) {
#pragma unroll
    for (int j = 0; j < 4; ++j) {
      int col = c0 + wcol + j * 16 + (l & 15);
      int hh = (col >> 6) & 7, d = col & 63;
      int m_base = m0 + wrow + i * 16 + ((l >> 4) * 4);
      int bb = m_base >> 12, n0 = m_base & 4095;
      size_t hb = (size_t)(bb * 8 + hh);
      if (which == 0) {
#pragma unroll
        for (int r = 0; r < 4; ++r)
          qh[(hb * 4096 + n0 + r) * 64 + d] = f2b(acc[i][j][r] * QSCALE);
      } else if (which == 1) {
#pragma unroll
        for (int r = 0; r < 4; ++r)
          kh[(hb * 4096 + n0 + r) * 64 + d] = f2b(acc[i][j][r]);
      } else {
        ushort4 hv;
        hv.x = f2b(acc[i][j][0]); hv.y = f2b(acc[i][j][1]);
        hv.z = f2b(acc[i][j][2]); hv.w = f2b(acc[i][j][3]);
#pragma unroll
        for (int r = 0; r < 4; ++r)
          vh[(hb * 4096 + n0 + r) * 64 + d] = (&hv.x)[r];
        *(ushort4*)&vTh[(hb * 64 + d) * 4096 + n0] = hv;
      }
    }
  }
}

// landmark means (l=16) from bf16 q/k; outputs f32 + bf16
__global__ __launch_bounds__(256) void k_land(const unsigned short* __restrict__ q,
                                              const unsigned short* __restrict__ k,
                                              float* __restrict__ ql,
                                              float* __restrict__ kl,
                                              unsigned short* __restrict__ qlh,
                                              unsigned short* __restrict__ klh) {
  int idx = blockIdx.x * 256 + threadIdx.x;
  int sel = idx >= (BH * MLAND * DHEAD);
  int e = sel ? idx - BH * MLAND * DHEAD : idx;
  int bh = e >> 14; int m = (e >> 6) & 255; int d = e & 63;
  const unsigned short* src = sel ? k : q;
  size_t base = ((size_t)bh * 4096 + m * 16) * 64 + d;
  float s = 0;
#pragma unroll
  for (int t = 0; t < 16; ++t) s += b2f(src[base + t * 64]);
  float val = s * (1.f / 16.f);
  (sel ? kl : ql)[e] = val;
  (sel ? klh : qlh)[e] = f2b(val);
}

// sim2 + row softmax -> a2 fp32 + bf16
__global__ __launch_bounds__(256) void k_sim2(const float* __restrict__ ql,
                                              const float* __restrict__ kl,
                                              float* __restrict__ a2,
                                              unsigned short* __restrict__ a2h) {
  __shared__ float qs[64];
  __shared__ float s4[4];
  int i = blockIdx.x, bh = blockIdx.y, tid = threadIdx.x;
  if (tid < 16) ((float4*)qs)[tid] = ((const float4*)(ql + ((size_t)bh * 256 + i) * 64))[tid];
  __syncthreads();
  const float* kr = kl + ((size_t)bh * 256 + tid) * 64;
  float s = 0;
#pragma unroll
  for (int d = 0; d < 64; d += 4) {
    float4 kv = *(const float4*)&kr[d];
    s += qs[d] * kv.x + qs[d + 1] * kv.y + qs[d + 2] * kv.z + qs[d + 3] * kv.w;
  }
  float mx = block_red(s, s4, false);
  float p = expf(s - mx);
  float tot = block_red(p, s4, true);
  float val = p / tot;
  a2[((size_t)bh * 256 + i) * 256 + tid] = val;
  a2h[((size_t)bh * 256 + i) * 256 + tid] = f2b(val);
}

__global__ __launch_bounds__(256) void k_pinv_red(const float* __restrict__ a2,
                                                  unsigned* __restrict__ scal) {
  __shared__ float s4[4];
  int bh = blockIdx.x, tid = threadIdx.x;
  const float* m = a2 + (size_t)bh * 65536;
  float cs = 0;
  for (int i = 0; i < 256; ++i) cs += fabsf(m[(size_t)i * 256 + tid]);
  float rs = 0;
  const float* row = m + (size_t)tid * 256;
  for (int j = 0; j < 256; j += 4) {
    float4 v = *(const float4*)&row[j];
    rs += fabsf(v.x) + fabsf(v.y) + fabsf(v.z) + fabsf(v.w);
  }
  float mc = block_red(cs, s4, false);
  float mr = block_red(rs, s4, false);
  if (tid == 0) {
    atomicMax(&scal[0], __float_as_uint(mr));
    atomicMax(&scal[1], __float_as_uint(mc));
  }
}

// z0 = a2^T / (R*C) in bf16, plus transposed copy
__global__ __launch_bounds__(256) void k_z0h(const float* __restrict__ a2,
                                             const unsigned* __restrict__ scal,
                                             unsigned short* __restrict__ zh,
                                             unsigned short* __restrict__ zTh) {
  int idx = blockIdx.x * 256 + threadIdx.x;
  float inv = 1.f / (__uint_as_float(scal[0]) * __uint_as_float(scal[1]));
  int bh = idx >> 16, r = (idx >> 8) & 255, c = idx & 255;
  zh[idx]  = f2b(a2[((size_t)bh << 16) + (c << 8) + r] * inv);
  zTh[idx] = f2b(a2[idx] * inv);
}

// pinv GEMM: 64x64 tile, full-K LDS staging. 1D grid of 256 blocks with
// XCD-colocating decode: bh = id & 15 -> all 16 blocks of a bh share id%8 (same XCD L2).
__global__ __launch_bounds__(256) void k_pg2(const unsigned short* __restrict__ A,
                                             const unsigned short* __restrict__ Bsrc,
                                             unsigned short* __restrict__ C,
                                             unsigned short* __restrict__ CT,
                                             float g, float bI, float s) {
  __shared__ short As[8 * 64 * 32], Bs[8 * 64 * 32];   // 32 KB + 32 KB
  int tid = threadIdx.x, l = tid & 63, w = tid >> 6;
  int bh = blockIdx.x & 15, t = blockIdx.x >> 4;
  int i0 = (t >> 2) * 64, j0 = (t & 3) * 64;
  A += (size_t)bh * 65536; Bsrc += (size_t)bh * 65536;

  // stage A: 8 k-chunks of [64][32], async
#pragma unroll
  for (int ks = 0; ks < 8; ++ks)
    stage_lds<64>(A + (size_t)i0 * 256 + ks * 32, 256, As + ks * 2048, tid);

  // stage B with transform: Bop[n][k] = g*Bsrc[n][k] + bI*(n==k)
#pragma unroll
  for (int u = tid; u < 2048; u += 256) {
    int r = u >> 5, q8 = u & 31;           // row 0..63, uint4 index 0..31
    int ks = q8 >> 2, p = q8 & 3;
    uint4 vv = *(const uint4*)(Bsrc + (size_t)(j0 + r) * 256 + q8 * 8);
    unsigned short* e = (unsigned short*)&vv;
    int n = j0 + r, kb = q8 * 8;
#pragma unroll
    for (int q = 0; q < 8; ++q) {
      float f = b2f(e[q]) * g + ((n == kb + q) ? bI : 0.f);
      e[q] = f2b(f);
    }
    *(uint4*)(Bs + ks * 2048 + r * 32 + p * 8) = vv;
  }
  __syncthreads();

  // K-loop: pure LDS + MFMA, no barriers. Wave w owns rows w*16..w*16+15.
  int lr = l & 15, lk = (l >> 4) * 8;
  f32x4 acc[4] = {};
#pragma unroll
  for (int ks = 0; ks < 8; ++ks) {
    const short* Ac = As + ks * 2048;
    const short* Bc = Bs + ks * 2048;
    bf16x8 af = *(const bf16x8*)&Ac[(w * 16 + lr) * 32 + lk];
#pragma unroll
    for (int j = 0; j < 4; ++j) {
      bf16x8 bf_ = *(const bf16x8*)&Bc[(j * 16 + lr) * 32 + lk];
      acc[j] = __builtin_amdgcn_mfma_f32_16x16x32_bf16(af, bf_, acc[j], 0, 0, 0);
    }
  }

#pragma unroll
  for (int j = 0; j < 4; ++j) {
    int col = j0 + j * 16 + lr;
    int row0 = i0 + w * 16 + (l >> 4) * 4;
    ushort4 hv;
    hv.x = f2b(acc[j][0] * s); hv.y = f2b(acc[j][1] * s);
    hv.z = f2b(acc[j][2] * s); hv.w = f2b(acc[j][3] * s);
    if (CT) *(ushort4*)&CT[(size_t)bh * 65536 + (size_t)col * 256 + row0] = hv;
    if (C) {
      unsigned short* cb = C + (size_t)bh * 65536 + (size_t)row0 * 256 + col;
      cb[0] = hv.x; cb[256] = hv.y; cb[512] = hv.z; cb[768] = hv.w;
    }
  }
}

// sim3 = q_land @ k^T -> bf16 [bh][256][4096] (raw scores, softmax deferred)
__global__ __launch_bounds__(256) void k_sim3_mfma(const unsigned short* __restrict__ qlh,
                                                   const unsigned short* __restrict__ kh,
                                                   unsigned short* __restrict__ sim3h) {
  __shared__ short As[128 * 32], Bs[128 * 32];
  int tid = threadIdx.x, l = tid & 63, wid = tid >> 6;
  int wrow = (wid >> 1) * 64, wcol = (wid & 1) * 64;
  int bh = blockIdx.z;
  int m0 = blockIdx.y * 128, n0 = blockIdx.x * 128;
  const unsigned short* A = qlh + (size_t)bh * 256 * 64;
  const unsigned short* B = kh + (size_t)bh * 4096 * 64;
  f32x4 acc[4][4] = {};
  for (int k0 = 0; k0 < 64; k0 += 32) {
    __syncthreads();
    stage_lds<128>(A + (size_t)m0 * 64 + k0, 64, As, tid);
    stage_lds<128>(B + (size_t)n0 * 64 + k0, 64, Bs, tid);
    __syncthreads();
    mma_step32(As, Bs, wrow, wcol, l, acc);
  }
  unsigned short* Cm = sim3h + (size_t)bh * 1048576;
#pragma unroll
  for (int i = 0; i < 4; ++i)
#pragma unroll
    for (int j = 0; j < 4; ++j) {
      int col = n0 + wcol + j * 16 + (l & 15);
      int row0 = m0 + wrow + i * 16 + (l >> 4) * 4;
#pragma unroll
      for (int r = 0; r < 4; ++r)
        Cm[(size_t)(row0 + r) * 4096 + col] = f2b(acc[i][j][r]);
    }
}

// per-row max and 1/sum(exp) of sim3 rows (read-only) -> rs[bh*256+m] = {max, inv}
__global__ __launch_bounds__(256) void k_rowstat(const unsigned short* __restrict__ sim,
                                                 float* __restrict__ rs) {
  __shared__ float s4[4];
  int m = blockIdx.x, bh = blockIdx.y, tid = threadIdx.x;
  const unsigned short* row = sim + ((size_t)bh * 256 + m) * 4096;
  float v[16];
  float mx = -1e30f;
#pragma unroll
  for (int i = 0; i < 16; ++i) { v[i] = b2f(row[i * 256 + tid]); mx = fmaxf(mx, v[i]); }
  mx = block_red(mx, s4, false);
  float ssum = 0;
#pragma unroll
  for (int i = 0; i < 16; ++i) ssum += expf(v[i] - mx);
  ssum = block_red(ssum, s4, true);
  if (tid == 0) {
    rs[(size_t)(bh * 256 + m) * 2]     = mx;
    rs[(size_t)(bh * 256 + m) * 2 + 1] = 1.f / ssum;
  }
}

// a3 @ v split-K (kc=16, chunk=256, 8 inner steps), softmax on A-stage,
// issue-early prefetch of next chunk's A-registers overlapping MFMA (T14).
__global__ __launch_bounds__(256) void k_a3v_mfma(const unsigned short* __restrict__ a3h,
                                                  const unsigned short* __restrict__ vTh,
                                                  const float* __restrict__ rs,
                                                  float* __restrict__ part) {
  __shared__ short As[256 * 32], Bs[64 * 32];
  int tid = threadIdx.x, l = tid & 63, wid = tid >> 6;
  int wrow = wid * 64, wcol = 0;
  int kc = blockIdx.x, bh = blockIdx.z;     // kc in [0,16)
  const unsigned short* A = a3h + (size_t)bh * 1048576 + kc * 256;
  const unsigned short* B = vTh + (size_t)bh * 262144 + kc * 256;
  rs += (size_t)bh * 512;
  const int rA = tid >> 2, cA8 = (tid & 3) * 8;   // per-thread A slot
  f32x4 acc[4][4] = {};
  uint4 pre[4];
  // prefetch chunk 0
#pragma unroll
  for (int p = 0; p < 4; ++p)
    pre[p] = *(const uint4*)(A + (size_t)(rA + 64 * p) * 4096 + cA8);
#pragma unroll 1
  for (int ks = 0; ks < 8; ++ks) {
    __syncthreads();
    // transform + write prefetched A to LDS
#pragma unroll
    for (int p = 0; p < 4; ++p) {
      int r = rA + 64 * p;
      uint4 vv = pre[p];
      unsigned short* e = (unsigned short*)&vv;
      float m_ = rs[r * 2], inv_ = rs[r * 2 + 1];
#pragma unroll
      for (int q = 0; q < 8; ++q)
        e[q] = f2b(expf(b2f(e[q]) - m_) * inv_);
      *(uint4*)(As + r * 32 + cA8) = vv;
    }
    stage_lds<64>(B + ks * 32, 4096, Bs, tid);
    __syncthreads();
    if (ks < 7) {
      // issue next chunk's loads before MFMA (overlap)
#pragma unroll
      for (int p = 0; p < 4; ++p)
        pre[p] = *(const uint4*)(A + (size_t)(rA + 64 * p) * 4096 + (ks + 1) * 32 + cA8);
    }
    mma_step32(As, Bs, wrow, wcol, l, acc);
  }
  float* P = part + ((size_t)(kc * 16 + bh)) * 16384;
#pragma unroll
  for (int i = 0; i < 4; ++i)
#pragma unroll
    for (int j = 0; j < 4; ++j) {
      int col = j * 16 + (l & 15);
      int row0 = wrow + i * 16 + (l >> 4) * 4;
#pragma unroll
      for (int r = 0; r < 4; ++r)
        P[(size_t)(row0 + r) * 64 + col] = acc[i][j][r];
    }
}

// reduce split-K partials (16) -> a3vT bf16 [bh][64 d][256 m]
// coalesced: d in low bits of thread index -> consecutive lanes read consecutive floats
__global__ __launch_bounds__(256) void k_a3v_redT(const float* __restrict__ part,
                                                  unsigned short* __restrict__ a3vT) {
  int idx = blockIdx.x * 256 + threadIdx.x;   // 262144
  int d = idx & 63, m = (idx >> 6) & 255, bh = idx >> 14;
  float s = 0;
#pragma unroll
  for (int c = 0; c < 16; ++c) s += part[((size_t)(c * 16 + bh) * 256 + m) * 64 + d];
  a3vT[(size_t)bh * 16384 + d * 256 + m] = f2b(s);
}

// wm = z @ a3v -> wmT bf16 [bh][64 d][256 m]
__global__ __launch_bounds__(256) void k_wm_mfma(const unsigned short* __restrict__ zh,
                                                 const unsigned short* __restrict__ a3vTh,
                                                 unsigned short* __restrict__ wmTh) {
  __shared__ short As[256 * 32], Bs[64 * 32];
  int tid = threadIdx.x, l = tid & 63, wid = tid >> 6;
  int wrow = wid * 64, wcol = 0;
  int bh = blockIdx.z;
  const unsigned short* A = zh + (size_t)bh * 65536;
  const unsigned short* B = a3vTh + (size_t)bh * 16384;
  f32x4 acc[4][4] = {};
  for (int k0 = 0; k0 < 256; k0 += 32) {
    __syncthreads();
    stage_lds<256>(A + k0, 256, As, tid);
    stage_lds<64>(B + k0, 256, Bs, tid);
    __syncthreads();
    mma_step32(As, Bs, wrow, wcol, l, acc);
  }
  unsigned short* W = wmTh + (size_t)bh * 16384;
#pragma unroll
  for (int i = 0; i < 4; ++i)
#pragma unroll
    for (int j = 0; j < 4; ++j) {
      int col = j * 16 + (l & 15);                 // d
      int row0 = wrow + i * 16 + (l >> 4) * 4;     // m
#pragma unroll
      for (int r = 0; r < 4; ++r)
        W[(size_t)col * 256 + row0 + r] = f2b(acc[i][j][r]);
    }
}

// ---------------- fused attention tail, MFMA ----------------
// block = 128 tokens x 1 head, 512 threads (8 waves, 16 rows each)
#define FSM_Q    0
#define FSM_KL   16384
#define FSM_WMT  0
#define FSM_P    32768
#define FSM_OUT  0
#define FSM_V    32768
__global__ __launch_bounds__(512) void k_fused_mfma(const unsigned short* __restrict__ qh,
                                                    const unsigned short* __restrict__ klh,
                                                    const unsigned short* __restrict__ wmTh,
                                                    const unsigned short* __restrict__ vh,
                                                    const float* __restrict__ cw,
                                                    unsigned short* __restrict__ yh) {
  __shared__ char sm[55808];
  int tid = threadIdx.x, l = tid & 63, w = tid >> 6;
  int h = blockIdx.y, b = blockIdx.z, bh = b * HEADS + h;
  int n0 = blockIdx.x * 128;
  const char* qg = (const char*)(qh + ((size_t)bh * 4096 + n0) * 64);
  const char* kg = (const char*)(klh + (size_t)bh * 256 * 64);

  // stage q (swizzled) and kl (swizzled)
#pragma unroll
  for (int u = tid; u < 1024; u += 512) {
    int row = u >> 3, cb = (u & 7) * 16;
    *(uint4*)(sm + FSM_Q + row * 128 + (cb ^ ((row & 7) << 4))) =
        *(const uint4*)(qg + row * 128 + cb);
  }
#pragma unroll
  for (int u = tid; u < 2048; u += 512) {
    int row = u >> 3, cb = (u & 7) * 16;
    *(uint4*)(sm + FSM_KL + row * 128 + (cb ^ ((row & 7) << 4))) =
        *(const uint4*)(kg + row * 128 + cb);
  }
  __syncthreads();

  int lr = l & 15, lkb = (l >> 4) * 16;
  int arow = 16 * w + lr;
  int aswz = (arow & 7) << 4;
  f32x4 acc[16] = {};
#pragma unroll
  for (int ks = 0; ks < 2; ++ks) {
    bf16x8 af = *(const bf16x8*)(sm + FSM_Q + arow * 128 + ((ks * 64 + lkb) ^ aswz));
#pragma unroll
    for (int j = 0; j < 16; ++j) {
      int brow = j * 16 + lr;
      bf16x8 bf_ = *(const bf16x8*)(sm + FSM_KL + brow * 128 + ((ks * 64 + lkb) ^ ((brow & 7) << 4)));
      acc[j] = __builtin_amdgcn_mfma_f32_16x16x32_bf16(af, bf_, acc[j], 0, 0, 0);
    }
  }

  // in-register row softmax (row on 16 lanes x 16 j-frags)
#pragma unroll
  for (int r = 0; r < 4; ++r) {
    float mx = -1e30f;
#pragma unroll
    for (int j = 0; j < 16; ++j) mx = fmaxf(mx, acc[j][r]);
#pragma unroll
    for (int o = 8; o; o >>= 1) mx = fmaxf(mx, __shfl_xor(mx, o));
    float s = 0.f;
#pragma unroll
    for (int j = 0; j < 16; ++j) { float e = expf(acc[j][r] - mx); acc[j][r] = e; s += e; }
#pragma unroll
    for (int o = 8; o; o >>= 1) s += __shfl_xor(s, o);
    float inv = 1.f / s;
#pragma unroll
    for (int j = 0; j < 16; ++j) acc[j][r] *= inv;
  }
  __syncthreads();

  // stage wmT (swizzled)
  const char* wg = (const char*)(wmTh + (size_t)bh * 16384);
#pragma unroll
  for (int u = tid; u < 2048; u += 512) {
    int row = u >> 5, cb = (u & 31) * 16;
    *(uint4*)(sm + FSM_WMT + row * 512 + (cb ^ ((row & 7) << 4))) =
        *(const uint4*)(wg + row * 512 + cb);
  }

  f32x4 acc2[4] = {};
  int prow0 = 16 * w + (l >> 4) * 4;
#pragma unroll
  for (int mc = 0; mc < 4; ++mc) {
    __syncthreads();
#pragma unroll
    for (int j2 = 0; j2 < 4; ++j2)
#pragma unroll
      for (int r = 0; r < 4; ++r) {
        int row = prow0 + r;
        int colb = (j2 * 16 + lr) * 2;
        *(unsigned short*)(sm + FSM_P + row * 128 + (colb ^ ((row & 7) << 4))) =
            f2b(acc[mc * 4 + j2][r]);
      }
    __syncthreads();
#pragma unroll
    for (int ks = 0; ks < 2; ++ks) {
      bf16x8 af = *(const bf16x8*)(sm + FSM_P + arow * 128 + ((ks * 64 + lkb) ^ aswz));
#pragma unroll
      for (int j = 0; j < 4; ++j) {
        int brow = j * 16 + lr;
        bf16x8 bf_ = *(const bf16x8*)(sm + FSM_WMT + brow * 512 +
                                      ((mc * 128 + ks * 64 + lkb) ^ ((brow & 7) << 4)));
        acc2[j] = __builtin_amdgcn_mfma_f32_16x16x32_bf16(af, bf_, acc2[j], 0, 0, 0);
      }
    }
  }
  __syncthreads();

  // park PV result in LDS f32
#pragma unroll
  for (int j = 0; j < 4; ++j)
#pragma unroll
    for (int r = 0; r < 4; ++r)
      *(float*)(sm + FSM_OUT + (prow0 + r) * 256 + (j * 16 + lr) * 4) = acc2[j][r];

  // stage v halo bf16 [160 rows x 128B] at 144B stride
  const char* vg = (const char*)(vh + (size_t)bh * 4096 * 64);
#pragma unroll
  for (int u = tid; u < 1280; u += 512) {
    int row = u >> 3, cb = (u & 7) * 16;
    int n = n0 - 16 + row;
    uint4 vv; vv.x = 0; vv.y = 0; vv.z = 0; vv.w = 0;
    if (n >= 0 && n < 4096) vv = *(const uint4*)(vg + (size_t)n * 128 + cb);
    *(uint4*)(sm + FSM_V + row * 144 + cb) = vv;
  }
  __syncthreads();

  // conv + add + store
#pragma unroll
  for (int u = tid; u < 1024; u += 512) {
    int row = u >> 3, d8 = (u & 7) * 8;
    float r8[8] = {};
#pragma unroll 1
    for (int t = 0; t < KCONV; ++t) {
      float wt = cw[h * KCONV + t];  // uniform -> scalar load
      ushort4 a0 = *(const ushort4*)(sm + FSM_V + (row + t) * 144 + d8 * 2);
      ushort4 a1 = *(const ushort4*)(sm + FSM_V + (row + t) * 144 + d8 * 2 + 8);
      r8[0] += wt * b2f(a0.x); r8[1] += wt * b2f(a0.y);
      r8[2] += wt * b2f(a0.z); r8[3] += wt * b2f(a0.w);
      r8[4] += wt * b2f(a1.x); r8[5] += wt * b2f(a1.y);
      r8[6] += wt * b2f(a1.z); r8[7] += wt * b2f(a1.w);
    }
    const float* ol = (const float*)(sm + FSM_OUT + row * 256 + d8 * 4);
    ushort4 s0, s1;
    s0.x = f2b(r8[0] + ol[0]); s0.y = f2b(r8[1] + ol[1]);
    s0.z = f2b(r8[2] + ol[2]); s0.w = f2b(r8[3] + ol[3]);
    s1.x = f2b(r8[4] + ol[4]); s1.y = f2b(r8[5] + ol[5]);
    s1.z = f2b(r8[6] + ol[6]); s1.w = f2b(r8[7] + ol[7]);
    unsigned short* yp = yh + ((size_t)b * 4096 + n0 + row) * 512 + h * 64 + d8;
    *(ushort4*)yp = s0;
    *(ushort4*)(yp + 4) = s1;
  }
}

// out = x + y @ out_w^T + out_b  (MFMA)
__global__ __launch_bounds__(256) void k_outproj_mfma(const unsigned short* __restrict__ yh,
                                                      const unsigned short* __restrict__ owh,
                                                      const float* __restrict__ bias,
                                                      const float* __restrict__ x,
                                                      float* __restrict__ out) {
  __shared__ short As[128 * 32], Bs[128 * 32];
  int tid = threadIdx.x, l = tid & 63, wid = tid >> 6;
  int wrow = (wid >> 1) * 64, wcol = (wid & 1) * 64;
  int m0 = blockIdx.y * 128, c0 = blockIdx.x * 128;
  f32x4 acc[4][4] = {};
  for (int k0 = 0; k0 < 512; k0 += 32) {
    __syncthreads();
    stage_lds<128>(yh + (size_t)m0 * 512 + k0, 512, As, tid);
    stage_lds<128>(owh + (size_t)c0 * 512 + k0, 512, Bs, tid);
    __syncthreads();
    mma_step32(As, Bs, wrow, wcol, l, acc);
  }
#pragma unroll
  for (int i = 0; i < 4; ++i)
#pragma unroll
    for (int j = 0; j < 4; ++j) {
      int col = c0 + wcol + j * 16 + (l & 15);
      int row0 = m0 + wrow + i * 16 + (l >> 4) * 4;
      float bb = bias[col];
#pragma unroll
      for (int r = 0; r < 4; ++r) {
        size_t o = (size_t)(row0 + r) * 512 + col;
        out[o] = acc[i][j][r] + x[o] + bb;
      }
    }
}

// ---------------- launcher ----------------
extern "C" void kernel_launch(void* const* d_in, const int* in_sizes, int n_in,
                              void* d_out, int out_size, void* d_ws, size_t ws_size,
                              hipStream_t stream) {
  const float* x      = (const float*)d_in[0];
  const float* ln_w   = (const float*)d_in[1];
  const float* ln_b   = (const float*)d_in[2];
  const float* qkv_w  = (const float*)d_in[3];
  const float* out_w  = (const float*)d_in[4];
  const float* out_b  = (const float*)d_in[5];
  const float* conv_w = (const float*)d_in[6];
  float* out = (float*)d_out;

  unsigned short* vh  = (unsigned short*)WB(d_ws, 0);   // 8.4 MB
  float* part = (float*)WB(d_ws, 12);   // 16 partials: 16.8 MB (12..30)
  float* ql   = (float*)WB(d_ws, 48);
  float* kl   = (float*)WB(d_ws, 49);
  float* a2   = (float*)WB(d_ws, 50);
  float* rs   = (float*)WB(d_ws, 62);   // 32 KB row stats
  unsigned* scal = (unsigned*)WB(d_ws, 63);
  unsigned short* xnh  = (unsigned short*)WB(d_ws, 64);
  unsigned short* wqh  = (unsigned short*)WB(d_ws, 72);
  unsigned short* owh  = (unsigned short*)WB(d_ws, 74);
  unsigned short* kh   = (unsigned short*)WB(d_ws, 76);
  unsigned short* vTh  = (unsigned short*)WB(d_ws, 84);
  unsigned short* qlh  = (unsigned short*)WB(d_ws, 92);
  unsigned short* a2h  = (unsigned short*)WB(d_ws, 93);
  unsigned short* zA   = (unsigned short*)WB(d_ws, 95);
  unsigned short* zAT  = (unsigned short*)WB(d_ws, 97);
  unsigned short* zB   = (unsigned short*)WB(d_ws, 99);
  unsigned short* zBT  = (unsigned short*)WB(d_ws, 101);
  unsigned short* Am   = (unsigned short*)WB(d_ws, 103);
  unsigned short* AmT  = (unsigned short*)WB(d_ws, 105);
  unsigned short* W2T  = (unsigned short*)WB(d_ws, 107);
  unsigned short* W4T  = (unsigned short*)WB(d_ws, 109);
  unsigned short* sim3h= (unsigned short*)WB(d_ws, 111);
  unsigned short* a3vTh= (unsigned short*)WB(d_ws, 143);
  unsigned short* yh   = (unsigned short*)WB(d_ws, 144);
  unsigned short* qhb  = (unsigned short*)WB(d_ws, 152);
  unsigned short* klhb = (unsigned short*)WB(d_ws, 168);
  unsigned short* wmTh = (unsigned short*)WB(d_ws, 169);

  k_init<<<1, 64, 0, stream>>>(scal);
  k_ln_wconv<<<6144, 256, 0, stream>>>(x, ln_w, ln_b, qkv_w, out_w, xnh, wqh, owh);
  k_qkv_mfma<<<dim3(12, 64), 256, 0, stream>>>(xnh, wqh, qhb, kh, vh, vTh);
  k_land<<<2048, 256, 0, stream>>>(qhb, kh, ql, kl, qlh, klhb);
  k_sim2<<<dim3(256, 16), 256, 0, stream>>>(ql, kl, a2, a2h);
  k_pinv_red<<<16, 256, 0, stream>>>(a2, scal);
  k_z0h<<<4096, 256, 0, stream>>>(a2, scal, zA, zAT);

  unsigned short *zc = zA, *zcT = zAT, *zn = zB, *znT = zBT;
  for (int it = 0; it < 6; ++it) {
    k_pg2<<<256, 256, 0, stream>>>(a2h, zcT, Am, AmT, 1.f, 0.f, 1.f);
    k_pg2<<<256, 256, 0, stream>>>(Am, AmT, (unsigned short*)nullptr, W2T, -1.f, 7.f, 1.f);
    k_pg2<<<256, 256, 0, stream>>>(Am, W2T, (unsigned short*)nullptr, W4T, -1.f, 15.f, 1.f);
    k_pg2<<<256, 256, 0, stream>>>(zc, W4T, zn, znT, -1.f, 13.f, 0.25f);
    unsigned short* t;
    t = zc; zc = zn; zn = t;
    t = zcT; zcT = znT; znT = t;
  }

  k_sim3_mfma<<<dim3(32, 2, 16), 256, 0, stream>>>(qlh, kh, sim3h);
  k_rowstat<<<dim3(256, 16), 256, 0, stream>>>(sim3h, rs);
  k_a3v_mfma<<<dim3(16, 1, 16), 256, 0, stream>>>(sim3h, vTh, rs, part);
  k_a3v_redT<<<1024, 256, 0, stream>>>(part, a3vTh);
  k_wm_mfma<<<dim3(1, 1, 16), 256, 0, stream>>>(zA, a3vTh, wmTh);
  k_fused_mfma<<<dim3(32, 8, 2), 512, 0, stream>>>(qhb, klhb, wmTh, vh, conv_w, yh);
  k_outproj_mfma<<<dim3(4, 64), 256, 0, stream>>>(yh, owh, out_b, x, out);
}

// Round 16
// 315.818 us; speedup vs baseline: 5.0539x; 1.0355x over previous
//
#include <hip/hip_runtime.h>
#include <math.h>

// ---------------- problem constants ----------------
#define DIMD  512
#define NSEQ  4096
#define BATCH 2
#define HEADS 8
#define DHEAD 64
#define MLAND 256
#define BH    (BATCH*HEADS)      // 16
#define QSCALE 0.125f
#define LN_EPS 1e-5f
#define KCONV 33

typedef __attribute__((ext_vector_type(8))) short bf16x8;
typedef __attribute__((ext_vector_type(4))) float f32x4;

// ---------------- workspace layout (MB offsets) ----------------
#define WB(p, mb) ((char*)(p) + (size_t)(mb) * 1048576ull)

// ---------------- helpers ----------------
__device__ __forceinline__ unsigned short f2b(float f) {
  unsigned u = __float_as_uint(f);
  return (unsigned short)((u + 0x7FFFu + ((u >> 16) & 1u)) >> 16);
}
__device__ __forceinline__ float b2f(unsigned short h) {
  return __uint_as_float(((unsigned)h) << 16);
}

__device__ __forceinline__ float block_red(float v, float* s4, bool sum) {
#pragma unroll
  for (int o = 32; o; o >>= 1) {
    float t = __shfl_xor(v, o);
    v = sum ? v + t : fmaxf(v, t);
  }
  int wid = threadIdx.x >> 6;
  if ((threadIdx.x & 63) == 0) s4[wid] = v;
  __syncthreads();
  float r = sum ? (s4[0] + s4[1] + s4[2] + s4[3])
                : fmaxf(fmaxf(s4[0], s4[1]), fmaxf(s4[2], s4[3]));
  __syncthreads();
  return r;
}

// async global->LDS, 16B per lane; LDS dest = wave-uniform base + lane*16
__device__ __forceinline__ void gload16(const unsigned short* g, short* lds) {
  __builtin_amdgcn_global_load_lds(
      (const __attribute__((address_space(1))) void*)g,
      (__attribute__((address_space(3))) void*)lds, 16, 0, 0);
}

// stage ROWS x 32 bf16 tile (row-major, contiguous k) into LDS via global_load_lds.
// lane l <-> row l/4, col (l%4)*16B  == linear row-major [ROWS][32] shorts.
template<int ROWS>
__device__ __forceinline__ void stage_lds(const unsigned short* __restrict__ g, int ld,
                                          short* lds, int tid) {
  int l = tid & 63, w = tid >> 6;
  int r_in = l >> 2, c8 = (l & 3) * 8;
  constexpr int PER = ROWS / 64;   // instructions per wave
#pragma unroll
  for (int p = 0; p < PER; ++p) {
    int r0 = (w * PER + p) * 16;
    gload16(g + (size_t)(r0 + r_in) * ld + c8, lds + r0 * 32);
  }
}

// wave computes 64x64 from LDS tiles As[.][32], Bs[.][32] (both [row][k] bf16)
__device__ __forceinline__ void mma_step32(const short* As, const short* Bs,
                                           int wrow, int wcol, int l, f32x4 acc[4][4]) {
  int lr = l & 15, lk = (l >> 4) * 8;
  bf16x8 af[4], bf_[4];
#pragma unroll
  for (int f = 0; f < 4; ++f) {
    af[f]  = *(const bf16x8*)&As[(wrow + f * 16 + lr) * 32 + lk];
    bf_[f] = *(const bf16x8*)&Bs[(wcol + f * 16 + lr) * 32 + lk];
  }
#pragma unroll
  for (int i = 0; i < 4; ++i)
#pragma unroll
    for (int j = 0; j < 4; ++j)
      acc[i][j] = __builtin_amdgcn_mfma_f32_16x16x32_bf16(af[i], bf_[j], acc[i][j], 0, 0, 0);
}

// ---------------- kernels ----------------

// fused: blocks [0,2048) LayerNorm -> bf16 xn; blocks [2048,6144) weight conversion
// block 2048 also zeroes scal (runs before any consumer kernel: stream-ordered)
__global__ __launch_bounds__(256) void k_ln_wconv(const float* __restrict__ x,
                                                  const float* __restrict__ w,
                                                  const float* __restrict__ b,
                                                  const float* __restrict__ qkvw,
                                                  const float* __restrict__ outw,
                                                  unsigned short* __restrict__ xnh,
                                                  unsigned short* __restrict__ wqh,
                                                  unsigned short* __restrict__ owh,
                                                  unsigned* __restrict__ scal) {
  if (blockIdx.x >= 2048) {
    int idx = (blockIdx.x - 2048) * 256 + threadIdx.x;
    if (idx < 786432) wqh[idx] = f2b(qkvw[idx]);
    else owh[idx - 786432] = f2b(outw[idx - 786432]);
    if (blockIdx.x == 2048 && threadIdx.x < 4) scal[threadIdx.x] = 0u;
    return;
  }
  int lane = threadIdx.x & 63;
  int row = blockIdx.x * 4 + (threadIdx.x >> 6);
  const float* xr = x + (size_t)row * DIMD;
  float4 v0 = *(const float4*)&xr[lane * 8];
  float4 v1 = *(const float4*)&xr[lane * 8 + 4];
  float s  = v0.x + v0.y + v0.z + v0.w + v1.x + v1.y + v1.z + v1.w;
  float ss = v0.x*v0.x + v0.y*v0.y + v0.z*v0.z + v0.w*v0.w
           + v1.x*v1.x + v1.y*v1.y + v1.z*v1.z + v1.w*v1.w;
#pragma unroll
  for (int o = 32; o; o >>= 1) { s += __shfl_xor(s, o); ss += __shfl_xor(ss, o); }
  float mu = s * (1.f / 512.f);
  float var = ss * (1.f / 512.f) - mu * mu;
  float rstd = rsqrtf(var + LN_EPS);
  float4 w0 = *(const float4*)&w[lane * 8];
  float4 w1 = *(const float4*)&w[lane * 8 + 4];
  float4 b0 = *(const float4*)&b[lane * 8];
  float4 b1 = *(const float4*)&b[lane * 8 + 4];
  float o0x = (v0.x - mu) * rstd * w0.x + b0.x;
  float o0y = (v0.y - mu) * rstd * w0.y + b0.y;
  float o0z = (v0.z - mu) * rstd * w0.z + b0.z;
  float o0w = (v0.w - mu) * rstd * w0.w + b0.w;
  float o1x = (v1.x - mu) * rstd * w1.x + b1.x;
  float o1y = (v1.y - mu) * rstd * w1.y + b1.y;
  float o1z = (v1.z - mu) * rstd * w1.z + b1.z;
  float o1w = (v1.w - mu) * rstd * w1.w + b1.w;
  uint4 pk;
  pk.x = (unsigned)f2b(o0x) | ((unsigned)f2b(o0y) << 16);
  pk.y = (unsigned)f2b(o0z) | ((unsigned)f2b(o0w) << 16);
  pk.z = (unsigned)f2b(o1x) | ((unsigned)f2b(o1y) << 16);
  pk.w = (unsigned)f2b(o1z) | ((unsigned)f2b(o1w) << 16);
  *(uint4*)&xnh[(size_t)row * DIMD + lane * 8] = pk;
}

// QKV: C[m,c]=sum_k xn[m,k]*W[c,k]; BK=64 (two 32-chunks per barrier pair)
__global__ __launch_bounds__(256) void k_qkv_mfma(const unsigned short* __restrict__ xnh,
                                                  const unsigned short* __restrict__ wqh,
                                                  unsigned short* __restrict__ qh,
                                                  unsigned short* __restrict__ kh,
                                                  unsigned short* __restrict__ vh,
                                                  unsigned short* __restrict__ vTh) {
  __shared__ short As[2 * 128 * 32], Bs[2 * 128 * 32];
  int tid = threadIdx.x, l = tid & 63, wid = tid >> 6;
  int wrow = (wid >> 1) * 64, wcol = (wid & 1) * 64;
  int m0 = blockIdx.y * 128, c0 = blockIdx.x * 128;
  f32x4 acc[4][4] = {};
  for (int k0 = 0; k0 < 512; k0 += 64) {
    __syncthreads();
    stage_lds<128>(xnh + (size_t)m0 * 512 + k0, 512, As, tid);
    stage_lds<128>(xnh + (size_t)m0 * 512 + k0 + 32, 512, As + 4096, tid);
    stage_lds<128>(wqh + (size_t)c0 * 512 + k0, 512, Bs, tid);
    stage_lds<128>(wqh + (size_t)c0 * 512 + k0 + 32, 512, Bs + 4096, tid);
    __syncthreads();
    mma_step32(As, Bs, wrow, wcol, l, acc);
    mma_step32(As + 4096, Bs + 4096, wrow, wcol, l, acc);
  }
  const int which = c0 >> 9;
#pragma unroll
  for (int i = 0; i < 4; ++i) {
#pragma unroll
    for (int j = 0; j < 4; ++j) {
      int col = c0 + wcol + j * 16 + (l & 15);
      int hh = (col >> 6) & 7, d = col & 63;
      int m_base = m0 + wrow + i * 16 + ((l >> 4) * 4);
      int bb = m_base >> 12, n0 = m_base & 4095;
      size_t hb = (size_t)(bb * 8 + hh);
      if (which == 0) {
#pragma unroll
        for (int r = 0; r < 4; ++r)
          qh[(hb * 4096 + n0 + r) * 64 + d] = f2b(acc[i][j][r] * QSCALE);
      } else if (which == 1) {
#pragma unroll
        for (int r = 0; r < 4; ++r)
          kh[(hb * 4096 + n0 + r) * 64 + d] = f2b(acc[i][j][r]);
      } else {
        ushort4 hv;
        hv.x = f2b(acc[i][j][0]); hv.y = f2b(acc[i][j][1]);
        hv.z = f2b(acc[i][j][2]); hv.w = f2b(acc[i][j][3]);
#pragma unroll
        for (int r = 0; r < 4; ++r)
          vh[(hb * 4096 + n0 + r) * 64 + d] = (&hv.x)[r];
        *(ushort4*)&vTh[(hb * 64 + d) * 4096 + n0] = hv;
      }
    }
  }
}

// landmark means (l=16) from bf16 q/k; outputs f32 + bf16
__global__ __launch_bounds__(256) void k_land(const unsigned short* __restrict__ q,
                                              const unsigned short* __restrict__ k,
                                              float* __restrict__ ql,
                                              float* __restrict__ kl,
                                              unsigned short* __restrict__ qlh,
                                              unsigned short* __restrict__ klh) {
  int idx = blockIdx.x * 256 + threadIdx.x;
  int sel = idx >= (BH * MLAND * DHEAD);
  int e = sel ? idx - BH * MLAND * DHEAD : idx;
  int bh = e >> 14; int m = (e >> 6) & 255; int d = e & 63;
  const unsigned short* src = sel ? k : q;
  size_t base = ((size_t)bh * 4096 + m * 16) * 64 + d;
  float s = 0;
#pragma unroll
  for (int t = 0; t < 16; ++t) s += b2f(src[base + t * 64]);
  float val = s * (1.f / 16.f);
  (sel ? kl : ql)[e] = val;
  (sel ? klh : qlh)[e] = f2b(val);
}

// sim2 + row softmax -> a2 fp32 + bf16
__global__ __launch_bounds__(256) void k_sim2(const float* __restrict__ ql,
                                              const float* __restrict__ kl,
                                              float* __restrict__ a2,
                                              unsigned short* __restrict__ a2h) {
  __shared__ float qs[64];
  __shared__ float s4[4];
  int i = blockIdx.x, bh = blockIdx.y, tid = threadIdx.x;
  if (tid < 16) ((float4*)qs)[tid] = ((const float4*)(ql + ((size_t)bh * 256 + i) * 64))[tid];
  __syncthreads();
  const float* kr = kl + ((size_t)bh * 256 + tid) * 64;
  float s = 0;
#pragma unroll
  for (int d = 0; d < 64; d += 4) {
    float4 kv = *(const float4*)&kr[d];
    s += qs[d] * kv.x + qs[d + 1] * kv.y + qs[d + 2] * kv.z + qs[d + 3] * kv.w;
  }
  float mx = block_red(s, s4, false);
  float p = expf(s - mx);
  float tot = block_red(p, s4, true);
  float val = p / tot;
  a2[((size_t)bh * 256 + i) * 256 + tid] = val;
  a2h[((size_t)bh * 256 + i) * 256 + tid] = f2b(val);
}

__global__ __launch_bounds__(256) void k_pinv_red(const float* __restrict__ a2,
                                                  unsigned* __restrict__ scal) {
  __shared__ float s4[4];
  int bh = blockIdx.x, tid = threadIdx.x;
  const float* m = a2 + (size_t)bh * 65536;
  float cs = 0;
  for (int i = 0; i < 256; ++i) cs += fabsf(m[(size_t)i * 256 + tid]);
  float rs = 0;
  const float* row = m + (size_t)tid * 256;
  for (int j = 0; j < 256; j += 4) {
    float4 v = *(const float4*)&row[j];
    rs += fabsf(v.x) + fabsf(v.y) + fabsf(v.z) + fabsf(v.w);
  }
  float mc = block_red(cs, s4, false);
  float mr = block_red(rs, s4, false);
  if (tid == 0) {
    atomicMax(&scal[0], __float_as_uint(mr));
    atomicMax(&scal[1], __float_as_uint(mc));
  }
}

// z0 = a2^T / (R*C) in bf16, plus transposed copy
__global__ __launch_bounds__(256) void k_z0h(const float* __restrict__ a2,
                                             const unsigned* __restrict__ scal,
                                             unsigned short* __restrict__ zh,
                                             unsigned short* __restrict__ zTh) {
  int idx = blockIdx.x * 256 + threadIdx.x;
  float inv = 1.f / (__uint_as_float(scal[0]) * __uint_as_float(scal[1]));
  int bh = idx >> 16, r = (idx >> 8) & 255, c = idx & 255;
  zh[idx]  = f2b(a2[((size_t)bh << 16) + (c << 8) + r] * inv);
  zTh[idx] = f2b(a2[idx] * inv);
}

// pinv GEMM: 64x64 tile, full-K LDS staging. 1D grid of 256 blocks with
// XCD-colocating decode: bh = id & 15 -> all 16 blocks of a bh share id%8 (same XCD L2).
__global__ __launch_bounds__(256) void k_pg2(const unsigned short* __restrict__ A,
                                             const unsigned short* __restrict__ Bsrc,
                                             unsigned short* __restrict__ C,
                                             unsigned short* __restrict__ CT,
                                             float g, float bI, float s) {
  __shared__ short As[8 * 64 * 32], Bs[8 * 64 * 32];   // 32 KB + 32 KB
  int tid = threadIdx.x, l = tid & 63, w = tid >> 6;
  int bh = blockIdx.x & 15, t = blockIdx.x >> 4;
  int i0 = (t >> 2) * 64, j0 = (t & 3) * 64;
  A += (size_t)bh * 65536; Bsrc += (size_t)bh * 65536;

  // stage A: 8 k-chunks of [64][32], async
#pragma unroll
  for (int ks = 0; ks < 8; ++ks)
    stage_lds<64>(A + (size_t)i0 * 256 + ks * 32, 256, As + ks * 2048, tid);

  // stage B with transform: Bop[n][k] = g*Bsrc[n][k] + bI*(n==k)
#pragma unroll
  for (int u = tid; u < 2048; u += 256) {
    int r = u >> 5, q8 = u & 31;           // row 0..63, uint4 index 0..31
    int ks = q8 >> 2, p = q8 & 3;
    uint4 vv = *(const uint4*)(Bsrc + (size_t)(j0 + r) * 256 + q8 * 8);
    unsigned short* e = (unsigned short*)&vv;
    int n = j0 + r, kb = q8 * 8;
#pragma unroll
    for (int q = 0; q < 8; ++q) {
      float f = b2f(e[q]) * g + ((n == kb + q) ? bI : 0.f);
      e[q] = f2b(f);
    }
    *(uint4*)(Bs + ks * 2048 + r * 32 + p * 8) = vv;
  }
  __syncthreads();

  // K-loop: pure LDS + MFMA, no barriers. Wave w owns rows w*16..w*16+15.
  int lr = l & 15, lk = (l >> 4) * 8;
  f32x4 acc[4] = {};
#pragma unroll
  for (int ks = 0; ks < 8; ++ks) {
    const short* Ac = As + ks * 2048;
    const short* Bc = Bs + ks * 2048;
    bf16x8 af = *(const bf16x8*)&Ac[(w * 16 + lr) * 32 + lk];
#pragma unroll
    for (int j = 0; j < 4; ++j) {
      bf16x8 bf_ = *(const bf16x8*)&Bc[(j * 16 + lr) * 32 + lk];
      acc[j] = __builtin_amdgcn_mfma_f32_16x16x32_bf16(af, bf_, acc[j], 0, 0, 0);
    }
  }

#pragma unroll
  for (int j = 0; j < 4; ++j) {
    int col = j0 + j * 16 + lr;
    int row0 = i0 + w * 16 + (l >> 4) * 4;
    ushort4 hv;
    hv.x = f2b(acc[j][0] * s); hv.y = f2b(acc[j][1] * s);
    hv.z = f2b(acc[j][2] * s); hv.w = f2b(acc[j][3] * s);
    if (CT) *(ushort4*)&CT[(size_t)bh * 65536 + (size_t)col * 256 + row0] = hv;
    if (C) {
      unsigned short* cb = C + (size_t)bh * 65536 + (size_t)row0 * 256 + col;
      cb[0] = hv.x; cb[256] = hv.y; cb[512] = hv.z; cb[768] = hv.w;
    }
  }
}

// sim3 = q_land @ k^T -> bf16 [bh][256][4096]; K=64 single-stage
__global__ __launch_bounds__(256) void k_sim3_mfma(const unsigned short* __restrict__ qlh,
                                                   const unsigned short* __restrict__ kh,
                                                   unsigned short* __restrict__ sim3h) {
  __shared__ short As[2 * 128 * 32], Bs[2 * 128 * 32];
  int tid = threadIdx.x, l = tid & 63, wid = tid >> 6;
  int wrow = (wid >> 1) * 64, wcol = (wid & 1) * 64;
  int bh = blockIdx.z;
  int m0 = blockIdx.y * 128, n0 = blockIdx.x * 128;
  const unsigned short* A = qlh + (size_t)bh * 256 * 64;
  const unsigned short* B = kh + (size_t)bh * 4096 * 64;
  f32x4 acc[4][4] = {};
  stage_lds<128>(A + (size_t)m0 * 64, 64, As, tid);
  stage_lds<128>(A + (size_t)m0 * 64 + 32, 64, As + 4096, tid);
  stage_lds<128>(B + (size_t)n0 * 64, 64, Bs, tid);
  stage_lds<128>(B + (size_t)n0 * 64 + 32, 64, Bs + 4096, tid);
  __syncthreads();
  mma_step32(As, Bs, wrow, wcol, l, acc);
  mma_step32(As + 4096, Bs + 4096, wrow, wcol, l, acc);
  unsigned short* Cm = sim3h + (size_t)bh * 1048576;
#pragma unroll
  for (int i = 0; i < 4; ++i)
#pragma unroll
    for (int j = 0; j < 4; ++j) {
      int col = n0 + wcol + j * 16 + (l & 15);
      int row0 = m0 + wrow + i * 16 + (l >> 4) * 4;
#pragma unroll
      for (int r = 0; r < 4; ++r)
        Cm[(size_t)(row0 + r) * 4096 + col] = f2b(acc[i][j][r]);
    }
}

// per-row max and 1/sum(exp) of sim3 rows (read-only) -> rs[bh*256+m] = {max, inv}
__global__ __launch_bounds__(256) void k_rowstat(const unsigned short* __restrict__ sim,
                                                 float* __restrict__ rs) {
  __shared__ float s4[4];
  int m = blockIdx.x, bh = blockIdx.y, tid = threadIdx.x;
  const unsigned short* row = sim + ((size_t)bh * 256 + m) * 4096;
  float v[16];
  float mx = -1e30f;
#pragma unroll
  for (int i = 0; i < 16; ++i) { v[i] = b2f(row[i * 256 + tid]); mx = fmaxf(mx, v[i]); }
  mx = block_red(mx, s4, false);
  float ssum = 0;
#pragma unroll
  for (int i = 0; i < 16; ++i) ssum += expf(v[i] - mx);
  ssum = block_red(ssum, s4, true);
  if (tid == 0) {
    rs[(size_t)(bh * 256 + m) * 2]     = mx;
    rs[(size_t)(bh * 256 + m) * 2 + 1] = 1.f / ssum;
  }
}

// a3 @ v split-K (kc=16, chunk=256, 8 inner steps), softmax on A-stage,
// issue-early prefetch of next chunk's A-registers overlapping MFMA (T14).
__global__ __launch_bounds__(256) void k_a3v_mfma(const unsigned short* __restrict__ a3h,
                                                  const unsigned short* __restrict__ vTh,
                                                  const float* __restrict__ rs,
                                                  float* __restrict__ part) {
  __shared__ short As[256 * 32], Bs[64 * 32];
  int tid = threadIdx.x, l = tid & 63, wid = tid >> 6;
  int wrow = wid * 64, wcol = 0;
  int kc = blockIdx.x, bh = blockIdx.z;     // kc in [0,16)
  const unsigned short* A = a3h + (size_t)bh * 1048576 + kc * 256;
  const unsigned short* B = vTh + (size_t)bh * 262144 + kc * 256;
  rs += (size_t)bh * 512;
  const int rA = tid >> 2, cA8 = (tid & 3) * 8;   // per-thread A slot
  f32x4 acc[4][4] = {};
  uint4 pre[4];
  // prefetch chunk 0
#pragma unroll
  for (int p = 0; p < 4; ++p)
    pre[p] = *(const uint4*)(A + (size_t)(rA + 64 * p) * 4096 + cA8);
#pragma unroll 1
  for (int ks = 0; ks < 8; ++ks) {
    __syncthreads();
    // transform + write prefetched A to LDS
#pragma unroll
    for (int p = 0; p < 4; ++p) {
      int r = rA + 64 * p;
      uint4 vv = pre[p];
      unsigned short* e = (unsigned short*)&vv;
      float m_ = rs[r * 2], inv_ = rs[r * 2 + 1];
#pragma unroll
      for (int q = 0; q < 8; ++q)
        e[q] = f2b(expf(b2f(e[q]) - m_) * inv_);
      *(uint4*)(As + r * 32 + cA8) = vv;
    }
    stage_lds<64>(B + ks * 32, 4096, Bs, tid);
    __syncthreads();
    if (ks < 7) {
      // issue next chunk's loads before MFMA (overlap)
#pragma unroll
      for (int p = 0; p < 4; ++p)
        pre[p] = *(const uint4*)(A + (size_t)(rA + 64 * p) * 4096 + (ks + 1) * 32 + cA8);
    }
    mma_step32(As, Bs, wrow, wcol, l, acc);
  }
  float* P = part + ((size_t)(kc * 16 + bh)) * 16384;
#pragma unroll
  for (int i = 0; i < 4; ++i)
#pragma unroll
    for (int j = 0; j < 4; ++j) {
      int col = j * 16 + (l & 15);
      int row0 = wrow + i * 16 + (l >> 4) * 4;
#pragma unroll
      for (int r = 0; r < 4; ++r)
        P[(size_t)(row0 + r) * 64 + col] = acc[i][j][r];
    }
}

// reduce split-K partials (16) -> a3vT bf16 [bh][64 d][256 m]
// coalesced: d in low bits of thread index -> consecutive lanes read consecutive floats
__global__ __launch_bounds__(256) void k_a3v_redT(const float* __restrict__ part,
                                                  unsigned short* __restrict__ a3vT) {
  int idx = blockIdx.x * 256 + threadIdx.x;   // 262144
  int d = idx & 63, m = (idx >> 6) & 255, bh = idx >> 14;
  float s = 0;
#pragma unroll
  for (int c = 0; c < 16; ++c) s += part[((size_t)(c * 16 + bh) * 256 + m) * 64 + d];
  a3vT[(size_t)bh * 16384 + d * 256 + m] = f2b(s);
}

// wm = z @ a3v -> wmT bf16 [bh][64 d][256 m]; grid (4 mtiles, 16 bh), full-K staging
__global__ __launch_bounds__(256) void k_wm_mfma(const unsigned short* __restrict__ zh,
                                                 const unsigned short* __restrict__ a3vTh,
                                                 unsigned short* __restrict__ wmTh) {
  __shared__ short As[8 * 64 * 32], Bs[8 * 64 * 32];
  int tid = threadIdx.x, l = tid & 63, w = tid >> 6;
  int m0 = blockIdx.x * 64, bh = blockIdx.y;
  const unsigned short* A = zh + (size_t)bh * 65536 + (size_t)m0 * 256;
  const unsigned short* B = a3vTh + (size_t)bh * 16384;
#pragma unroll
  for (int ks = 0; ks < 8; ++ks)
    stage_lds<64>(A + ks * 32, 256, As + ks * 2048, tid);
#pragma unroll
  for (int ks = 0; ks < 8; ++ks)
    stage_lds<64>(B + ks * 32, 256, Bs + ks * 2048, tid);
  __syncthreads();
  int lr = l & 15, lk = (l >> 4) * 8;
  f32x4 acc[4] = {};
#pragma unroll
  for (int ks = 0; ks < 8; ++ks) {
    const short* Ac = As + ks * 2048;
    const short* Bc = Bs + ks * 2048;
    bf16x8 af = *(const bf16x8*)&Ac[(w * 16 + lr) * 32 + lk];
#pragma unroll
    for (int j = 0; j < 4; ++j) {
      bf16x8 bf_ = *(const bf16x8*)&Bc[(j * 16 + lr) * 32 + lk];
      acc[j] = __builtin_amdgcn_mfma_f32_16x16x32_bf16(af, bf_, acc[j], 0, 0, 0);
    }
  }
  unsigned short* W = wmTh + (size_t)bh * 16384;
#pragma unroll
  for (int j = 0; j < 4; ++j) {
    int col = j * 16 + lr;                      // d
    int row0 = m0 + w * 16 + (l >> 4) * 4;      // m
#pragma unroll
    for (int r = 0; r < 4; ++r)
      W[(size_t)col * 256 + row0 + r] = f2b(acc[j][r]);
  }
}

// ---------------- fused attention tail, MFMA ----------------
// block = 128 tokens x 1 head, 512 threads (8 waves, 16 rows each)
#define FSM_Q    0
#define FSM_KL   16384
#define FSM_WMT  0
#define FSM_P    32768
#define FSM_OUT  0
#define FSM_V    32768
__global__ __launch_bounds__(512) void k_fused_mfma(const unsigned short* __restrict__ qh,
                                                    const unsigned short* __restrict__ klh,
                                                    const unsigned short* __restrict__ wmTh,
                                                    const unsigned short* __restrict__ vh,
                                                    const float* __restrict__ cw,
                                                    unsigned short* __restrict__ yh) {
  __shared__ char sm[55808];
  int tid = threadIdx.x, l = tid & 63, w = tid >> 6;
  int h = blockIdx.y, b = blockIdx.z, bh = b * HEADS + h;
  int n0 = blockIdx.x * 128;
  const char* qg = (const char*)(qh + ((size_t)bh * 4096 + n0) * 64);
  const char* kg = (const char*)(klh + (size_t)bh * 256 * 64);

  // stage q (swizzled) and kl (swizzled)
#pragma unroll
  for (int u = tid; u < 1024; u += 512) {
    int row = u >> 3, cb = (u & 7) * 16;
    *(uint4*)(sm + FSM_Q + row * 128 + (cb ^ ((row & 7) << 4))) =
        *(const uint4*)(qg + row * 128 + cb);
  }
#pragma unroll
  for (int u = tid; u < 2048; u += 512) {
    int row = u >> 3, cb = (u & 7) * 16;
    *(uint4*)(sm + FSM_KL + row * 128 + (cb ^ ((row & 7) << 4))) =
        *(const uint4*)(kg + row * 128 + cb);
  }
  __syncthreads();

  int lr = l & 15, lkb = (l >> 4) * 16;
  int arow = 16 * w + lr;
  int aswz = (arow & 7) << 4;
  f32x4 acc[16] = {};
#pragma unroll
  for (int ks = 0; ks < 2; ++ks) {
    bf16x8 af = *(const bf16x8*)(sm + FSM_Q + arow * 128 + ((ks * 64 + lkb) ^ aswz));
#pragma unroll
    for (int j = 0; j < 16; ++j) {
      int brow = j * 16 + lr;
      bf16x8 bf_ = *(const bf16x8*)(sm + FSM_KL + brow * 128 + ((ks * 64 + lkb) ^ ((brow & 7) << 4)));
      acc[j] = __builtin_amdgcn_mfma_f32_16x16x32_bf16(af, bf_, acc[j], 0, 0, 0);
    }
  }

  // in-register row softmax (row on 16 lanes x 16 j-frags)
#pragma unroll
  for (int r = 0; r < 4; ++r) {
    float mx = -1e30f;
#pragma unroll
    for (int j = 0; j < 16; ++j) mx = fmaxf(mx, acc[j][r]);
#pragma unroll
    for (int o = 8; o; o >>= 1) mx = fmaxf(mx, __shfl_xor(mx, o));
    float s = 0.f;
#pragma unroll
    for (int j = 0; j < 16; ++j) { float e = expf(acc[j][r] - mx); acc[j][r] = e; s += e; }
#pragma unroll
    for (int o = 8; o; o >>= 1) s += __shfl_xor(s, o);
    float inv = 1.f / s;
#pragma unroll
    for (int j = 0; j < 16; ++j) acc[j][r] *= inv;
  }
  __syncthreads();

  // stage wmT (swizzled)
  const char* wg = (const char*)(wmTh + (size_t)bh * 16384);
#pragma unroll
  for (int u = tid; u < 2048; u += 512) {
    int row = u >> 5, cb = (u & 31) * 16;
    *(uint4*)(sm + FSM_WMT + row * 512 + (cb ^ ((row & 7) << 4))) =
        *(const uint4*)(wg + row * 512 + cb);
  }

  f32x4 acc2[4] = {};
  int prow0 = 16 * w + (l >> 4) * 4;
#pragma unroll
  for (int mc = 0; mc < 4; ++mc) {
    __syncthreads();
#pragma unroll
    for (int j2 = 0; j2 < 4; ++j2)
#pragma unroll
      for (int r = 0; r < 4; ++r) {
        int row = prow0 + r;
        int colb = (j2 * 16 + lr) * 2;
        *(unsigned short*)(sm + FSM_P + row * 128 + (colb ^ ((row & 7) << 4))) =
            f2b(acc[mc * 4 + j2][r]);
      }
    __syncthreads();
#pragma unroll
    for (int ks = 0; ks < 2; ++ks) {
      bf16x8 af = *(const bf16x8*)(sm + FSM_P + arow * 128 + ((ks * 64 + lkb) ^ aswz));
#pragma unroll
      for (int j = 0; j < 4; ++j) {
        int brow = j * 16 + lr;
        bf16x8 bf_ = *(const bf16x8*)(sm + FSM_WMT + brow * 512 +
                                      ((mc * 128 + ks * 64 + lkb) ^ ((brow & 7) << 4)));
        acc2[j] = __builtin_amdgcn_mfma_f32_16x16x32_bf16(af, bf_, acc2[j], 0, 0, 0);
      }
    }
  }
  __syncthreads();

  // park PV result in LDS f32
#pragma unroll
  for (int j = 0; j < 4; ++j)
#pragma unroll
    for (int r = 0; r < 4; ++r)
      *(float*)(sm + FSM_OUT + (prow0 + r) * 256 + (j * 16 + lr) * 4) = acc2[j][r];

  // stage v halo bf16 [160 rows x 128B] at 144B stride
  const char* vg = (const char*)(vh + (size_t)bh * 4096 * 64);
#pragma unroll
  for (int u = tid; u < 1280; u += 512) {
    int row = u >> 3, cb = (u & 7) * 16;
    int n = n0 - 16 + row;
    uint4 vv; vv.x = 0; vv.y = 0; vv.z = 0; vv.w = 0;
    if (n >= 0 && n < 4096) vv = *(const uint4*)(vg + (size_t)n * 128 + cb);
    *(uint4*)(sm + FSM_V + row * 144 + cb) = vv;
  }
  __syncthreads();

  // conv + add + store
#pragma unroll
  for (int u = tid; u < 1024; u += 512) {
    int row = u >> 3, d8 = (u & 7) * 8;
    float r8[8] = {};
#pragma unroll 1
    for (int t = 0; t < KCONV; ++t) {
      float wt = cw[h * KCONV + t];  // uniform -> scalar load
      ushort4 a0 = *(const ushort4*)(sm + FSM_V + (row + t) * 144 + d8 * 2);
      ushort4 a1 = *(const ushort4*)(sm + FSM_V + (row + t) * 144 + d8 * 2 + 8);
      r8[0] += wt * b2f(a0.x); r8[1] += wt * b2f(a0.y);
      r8[2] += wt * b2f(a0.z); r8[3] += wt * b2f(a0.w);
      r8[4] += wt * b2f(a1.x); r8[5] += wt * b2f(a1.y);
      r8[6] += wt * b2f(a1.z); r8[7] += wt * b2f(a1.w);
    }
    const float* ol = (const float*)(sm + FSM_OUT + row * 256 + d8 * 4);
    ushort4 s0, s1;
    s0.x = f2b(r8[0] + ol[0]); s0.y = f2b(r8[1] + ol[1]);
    s0.z = f2b(r8[2] + ol[2]); s0.w = f2b(r8[3] + ol[3]);
    s1.x = f2b(r8[4] + ol[4]); s1.y = f2b(r8[5] + ol[5]);
    s1.z = f2b(r8[6] + ol[6]); s1.w = f2b(r8[7] + ol[7]);
    unsigned short* yp = yh + ((size_t)b * 4096 + n0 + row) * 512 + h * 64 + d8;
    *(ushort4*)yp = s0;
    *(ushort4*)(yp + 4) = s1;
  }
}

// out = x + y @ out_w^T + out_b  (MFMA, BK=64)
__global__ __launch_bounds__(256) void k_outproj_mfma(const unsigned short* __restrict__ yh,
                                                      const unsigned short* __restrict__ owh,
                                                      const float* __restrict__ bias,
                                                      const float* __restrict__ x,
                                                      float* __restrict__ out) {
  __shared__ short As[2 * 128 * 32], Bs[2 * 128 * 32];
  int tid = threadIdx.x, l = tid & 63, wid = tid >> 6;
  int wrow = (wid >> 1) * 64, wcol = (wid & 1) * 64;
  int m0 = blockIdx.y * 128, c0 = blockIdx.x * 128;
  f32x4 acc[4][4] = {};
  for (int k0 = 0; k0 < 512; k0 += 64) {
    __syncthreads();
    stage_lds<128>(yh + (size_t)m0 * 512 + k0, 512, As, tid);
    stage_lds<128>(yh + (size_t)m0 * 512 + k0 + 32, 512, As + 4096, tid);
    stage_lds<128>(owh + (size_t)c0 * 512 + k0, 512, Bs, tid);
    stage_lds<128>(owh + (size_t)c0 * 512 + k0 + 32, 512, Bs + 4096, tid);
    __syncthreads();
    mma_step32(As, Bs, wrow, wcol, l, acc);
    mma_step32(As + 4096, Bs + 4096, wrow, wcol, l, acc);
  }
#pragma unroll
  for (int i = 0; i < 4; ++i)
#pragma unroll
    for (int j = 0; j < 4; ++j) {
      int col = c0 + wcol + j * 16 + (l & 15);
      int row0 = m0 + wrow + i * 16 + (l >> 4) * 4;
      float bb = bias[col];
#pragma unroll
      for (int r = 0; r < 4; ++r) {
        size_t o = (size_t)(row0 + r) * 512 + col;
        out[o] = acc[i][j][r] + x[o] + bb;
      }
    }
}

// ---------------- launcher ----------------
extern "C" void kernel_launch(void* const* d_in, const int* in_sizes, int n_in,
                              void* d_out, int out_size, void* d_ws, size_t ws_size,
                              hipStream_t stream) {
  const float* x      = (const float*)d_in[0];
  const float* ln_w   = (const float*)d_in[1];
  const float* ln_b   = (const float*)d_in[2];
  const float* qkv_w  = (const float*)d_in[3];
  const float* out_w  = (const float*)d_in[4];
  const float* out_b  = (const float*)d_in[5];
  const float* conv_w = (const float*)d_in[6];
  float* out = (float*)d_out;

  unsigned short* vh  = (unsigned short*)WB(d_ws, 0);   // 8.4 MB
  float* part = (float*)WB(d_ws, 12);   // 16 partials: 16.8 MB (12..30)
  float* ql   = (float*)WB(d_ws, 48);
  float* kl   = (float*)WB(d_ws, 49);
  float* a2   = (float*)WB(d_ws, 50);
  float* rs   = (float*)WB(d_ws, 62);   // 32 KB row stats
  unsigned* scal = (unsigned*)WB(d_ws, 63);
  unsigned short* xnh  = (unsigned short*)WB(d_ws, 64);
  unsigned short* wqh  = (unsigned short*)WB(d_ws, 72);
  unsigned short* owh  = (unsigned short*)WB(d_ws, 74);
  unsigned short* kh   = (unsigned short*)WB(d_ws, 76);
  unsigned short* vTh  = (unsigned short*)WB(d_ws, 84);
  unsigned short* qlh  = (unsigned short*)WB(d_ws, 92);
  unsigned short* a2h  = (unsigned short*)WB(d_ws, 93);
  unsigned short* zA   = (unsigned short*)WB(d_ws, 95);
  unsigned short* zAT  = (unsigned short*)WB(d_ws, 97);
  unsigned short* zB   = (unsigned short*)WB(d_ws, 99);
  unsigned short* zBT  = (unsigned short*)WB(d_ws, 101);
  unsigned short* Am   = (unsigned short*)WB(d_ws, 103);
  unsigned short* AmT  = (unsigned short*)WB(d_ws, 105);
  unsigned short* W2T  = (unsigned short*)WB(d_ws, 107);
  unsigned short* W4T  = (unsigned short*)WB(d_ws, 109);
  unsigned short* sim3h= (unsigned short*)WB(d_ws, 111);
  unsigned short* a3vTh= (unsigned short*)WB(d_ws, 143);
  unsigned short* yh   = (unsigned short*)WB(d_ws, 144);
  unsigned short* qhb  = (unsigned short*)WB(d_ws, 152);
  unsigned short* klhb = (unsigned short*)WB(d_ws, 168);
  unsigned short* wmTh = (unsigned short*)WB(d_ws, 169);

  k_ln_wconv<<<6144, 256, 0, stream>>>(x, ln_w, ln_b, qkv_w, out_w, xnh, wqh, owh, scal);
  k_qkv_mfma<<<dim3(12, 64), 256, 0, stream>>>(xnh, wqh, qhb, kh, vh, vTh);
  k_land<<<2048, 256, 0, stream>>>(qhb, kh, ql, kl, qlh, klhb);
  k_sim2<<<dim3(256, 16), 256, 0, stream>>>(ql, kl, a2, a2h);
  k_pinv_red<<<16, 256, 0, stream>>>(a2, scal);
  k_z0h<<<4096, 256, 0, stream>>>(a2, scal, zA, zAT);

  unsigned short *zc = zA, *zcT = zAT, *zn = zB, *znT = zBT;
  for (int it = 0; it < 6; ++it) {
    k_pg2<<<256, 256, 0, stream>>>(a2h, zcT, Am, AmT, 1.f, 0.f, 1.f);
    k_pg2<<<256, 256, 0, stream>>>(Am, AmT, (unsigned short*)nullptr, W2T, -1.f, 7.f, 1.f);
    k_pg2<<<256, 256, 0, stream>>>(Am, W2T, (unsigned short*)nullptr, W4T, -1.f, 15.f, 1.f);
    k_pg2<<<256, 256, 0, stream>>>(zc, W4T, zn, znT, -1.f, 13.f, 0.25f);
    unsigned short* t;
    t = zc; zc = zn; zn = t;
    t = zcT; zcT = znT; znT = t;
  }

  k_sim3_mfma<<<dim3(32, 2, 16), 256, 0, stream>>>(qlh, kh, sim3h);
  k_rowstat<<<dim3(256, 16), 256, 0, stream>>>(sim3h, rs);
  k_a3v_mfma<<<dim3(16, 1, 16), 256, 0, stream>>>(sim3h, vTh, rs, part);
  k_a3v_redT<<<1024, 256, 0, stream>>>(part, a3vTh);
  k_wm_mfma<<<dim3(4, 16), 256, 0, stream>>>(zA, a3vTh, wmTh);
  k_fused_mfma<<<dim3(32, 8, 2), 512, 0, stream>>>(qhb, klhb, wmTh, vh, conv_w, yh);
  k_outproj_mfma<<<dim3(4, 64), 256, 0, stream>>>(yh, owh, out_b, x, out);
}